// Round 15
// baseline (630.814 us; speedup 1.0000x reference)
//
#include <hip/hip_runtime.h>
#include <math.h>

#define NNODES 100000
#define NEDGES 1600000
#define SCAN_CHUNK 1024
#define SCAN_BLOCKS ((NNODES + SCAN_CHUNK - 1) / SCAN_CHUNK)
#define FILL_PASSES 4
#define FILL_RANGE ((NNODES + FILL_PASSES - 1) / FILL_PASSES)
#define HPART 64
#define HRANGES 8
#define HRANGE ((NNODES + HRANGES - 1) / HRANGES)
#define DSB 64
#define DSCHUNK ((NNODES + DSB - 1) / DSB)
#define NBUCK 8
#define BUCKW ((NNODES + NBUCK - 1) / NBUCK)   // 12500-node src ranges

typedef _Float16 h16;
typedef _Float16 h16x4 __attribute__((ext_vector_type(4)));
typedef _Float16 h16x8 __attribute__((ext_vector_type(8)));
typedef float f32x4 __attribute__((ext_vector_type(4)));

__device__ __forceinline__ unsigned fenc(float f) {
  unsigned u = __float_as_uint(f);
  return (u >> 31) ? ~u : (u | 0x80000000u);
}
__device__ __forceinline__ float fdec(unsigned e) {
  unsigned u = (e & 0x80000000u) ? (e & 0x7fffffffu) : ~e;
  return __uint_as_float(u);
}

// ----------------------------- CSR build -----------------------------
__global__ __launch_bounds__(256) void k_hist(const int* __restrict__ dst,
                                              int* __restrict__ part, int E) {
  __shared__ int hloc[HRANGE];
  const int lo = blockIdx.y * HRANGE;
  const int hi = min(lo + HRANGE, NNODES);
  const int len = hi - lo;
  for (int i = threadIdx.x; i < len; i += 256) hloc[i] = 0;
  __syncthreads();
  int per = (E + gridDim.x - 1) / gridDim.x;
  int e0 = blockIdx.x * per, e1 = min(e0 + per, E);
  for (int e = e0 + threadIdx.x; e < e1; e += 256) {
    int d = dst[e] - lo;
    if ((unsigned)d < (unsigned)len) atomicAdd(&hloc[d], 1);
  }
  __syncthreads();
  int* mine = part + (size_t)blockIdx.x * NNODES + lo;
  for (int i = threadIdx.x * 4; i + 3 < len; i += 1024)
    *(int4*)&mine[i] = *(const int4*)&hloc[i];
}

__global__ __launch_bounds__(256) void k_scan1(const int* __restrict__ part,
                                               int* __restrict__ deg,
                                               int* __restrict__ bsums, int n) {
  __shared__ int red[4];
  int base = blockIdx.x * SCAN_CHUNK + threadIdx.x * 4;
  int d0 = 0, d1 = 0, d2 = 0, d3 = 0;
  if (base + 3 < n) {
    for (int p = 0; p < HPART; p++) {
      int4 v = *(const int4*)&part[(size_t)p * NNODES + base];
      d0 += v.x; d1 += v.y; d2 += v.z; d3 += v.w;
    }
    *(int4*)&deg[base] = make_int4(d0, d1, d2, d3);
  } else if (base < n) {
    int dd[4] = {};
    for (int p = 0; p < HPART; p++)
      for (int j = 0; j < 4; j++)
        if (base + j < n) dd[j] += part[(size_t)p * NNODES + base + j];
    for (int j = 0; j < 4; j++)
      if (base + j < n) deg[base + j] = dd[j];
    d0 = dd[0]; d1 = dd[1]; d2 = dd[2]; d3 = dd[3];
  }
  int s = d0 + d1 + d2 + d3;
  for (int m = 1; m < 64; m <<= 1) s += __shfl_xor(s, m);
  int wave = threadIdx.x >> 6, lane = threadIdx.x & 63;
  if (lane == 0) red[wave] = s;
  __syncthreads();
  if (threadIdx.x == 0) bsums[blockIdx.x] = red[0] + red[1] + red[2] + red[3];
}

__global__ __launch_bounds__(128) void k_scan2(int* __restrict__ bsums,
                                               int* __restrict__ offsets, int n) {
  __shared__ int sh[128];
  int t = threadIdx.x;
  int v = (t < SCAN_BLOCKS) ? bsums[t] : 0;
  sh[t] = v;
  __syncthreads();
  for (int off = 1; off < 128; off <<= 1) {
    int u = (t >= off) ? sh[t - off] : 0;
    __syncthreads();
    sh[t] += u;
    __syncthreads();
  }
  if (t < SCAN_BLOCKS) bsums[t] = sh[t] - v;
  if (t == 127) offsets[n] = sh[127];
}

__global__ __launch_bounds__(256) void k_scan3(const int* __restrict__ deg,
                                               const int* __restrict__ bsums,
                                               int* __restrict__ offsets,
                                               int* __restrict__ cursor, int n) {
  __shared__ int sh[256];
  int t = threadIdx.x;
  int base = blockIdx.x * SCAN_CHUNK + t * 4;
  int d[4];
#pragma unroll
  for (int j = 0; j < 4; j++) d[j] = (base + j < n) ? deg[base + j] : 0;
  int tsum = d[0] + d[1] + d[2] + d[3];
  sh[t] = tsum;
  __syncthreads();
  for (int off = 1; off < 256; off <<= 1) {
    int u = (t >= off) ? sh[t - off] : 0;
    __syncthreads();
    sh[t] += u;
    __syncthreads();
  }
  int run = bsums[blockIdx.x] + sh[t] - tsum;
#pragma unroll
  for (int j = 0; j < 4; j++) {
    if (base + j < n) { offsets[base + j] = run; cursor[base + j] = run; }
    run += d[j];
  }
}

__global__ void k_fill(const int* __restrict__ ei, int* __restrict__ cursor,
                       int* __restrict__ csr_src, int E, int lo, int hi) {
  int e = blockIdx.x * blockDim.x + threadIdx.x;
  if (e >= E) return;
  int dst = ei[E + e];
  if (dst < lo || dst >= hi) return;
  int slot = atomicAdd(&cursor[dst], 1);
  csr_src[slot] = ei[e];
}

// --------- bucket-sort each node's edge list by src range (L2 temporal blocking) ---------
// One wave per node. Exact permutation of the list; 8 buckets of 12500 src nodes.
__global__ __launch_bounds__(256) void k_bsort(const int* __restrict__ offsets,
                                               const int* __restrict__ csr,
                                               int* __restrict__ csr2, int n) {
  int wavei = threadIdx.x >> 6, lane = threadIdx.x & 63;
  int v = blockIdx.x * 4 + wavei;
  if (v >= n) return;
  int d0 = offsets[v], d1 = offsets[v + 1];
  int lc[NBUCK] = {};
  for (int e = d0 + lane; e < d1; e += 64) {
    int b = csr[e] / BUCKW;
#pragma unroll
    for (int bb = 0; bb < NBUCK; bb++) lc[bb] += (b == bb);
  }
#pragma unroll
  for (int bb = 0; bb < NBUCK; bb++)
    for (int m = 1; m < 64; m <<= 1) lc[bb] += __shfl_xor(lc[bb], m);
  int base[NBUCK];
  int run = d0;
#pragma unroll
  for (int bb = 0; bb < NBUCK; bb++) { base[bb] = run; run += lc[bb]; }
  for (int e0 = d0; e0 < d1; e0 += 64) {
    int e = e0 + lane;
    bool act = e < d1;
    int s = act ? csr[e] : 0;
    int b = act ? (s / BUCKW) : -1;
#pragma unroll
    for (int bb = 0; bb < NBUCK; bb++) {
      unsigned long long mask = __ballot(b == bb);
      if (b == bb) {
        int rank = __popcll(mask & ((1ull << lane) - 1ull));
        csr2[base[bb] + rank] = s;
      }
      base[bb] += __popcll(mask);
    }
  }
}

// ----------------------------- degree-sorted node permutation -----------------------------
__global__ __launch_bounds__(256) void k_dsA(const int* __restrict__ deg,
                                             int* __restrict__ sc, int n) {
  __shared__ int cnt[64];
  if (threadIdx.x < 64) cnt[threadIdx.x] = 0;
  __syncthreads();
  int i0 = blockIdx.x * DSCHUNK, i1 = min(i0 + DSCHUNK, n);
  for (int i = i0 + threadIdx.x; i < i1; i += 256)
    atomicAdd(&cnt[min(deg[i], 63)], 1);
  __syncthreads();
  if (threadIdx.x < 64) sc[blockIdx.x * 64 + threadIdx.x] = cnt[threadIdx.x];
}

__global__ __launch_bounds__(64) void k_dsB(int* __restrict__ sc) {
  __shared__ int tot[64];
  int k = threadIdx.x;
  int t = 0;
  for (int b = 0; b < DSB; b++) t += sc[b * 64 + k];
  tot[k] = t;
  __syncthreads();
  if (k == 0) {
    int run = 0;
    for (int j = 0; j < 64; j++) { int tt = tot[j]; tot[j] = run; run += tt; }
  }
  __syncthreads();
  int base = tot[k];
  for (int b = 0; b < DSB; b++) {
    int c = sc[b * 64 + k];
    sc[b * 64 + k] = base;
    base += c;
  }
}

__global__ __launch_bounds__(256) void k_dsC(const int* __restrict__ deg,
                                             const int* __restrict__ sc,
                                             int* __restrict__ perm, int n) {
  __shared__ int cnt[64];
  if (threadIdx.x < 64) cnt[threadIdx.x] = sc[blockIdx.x * 64 + threadIdx.x];
  __syncthreads();
  int i0 = blockIdx.x * DSCHUNK, i1 = min(i0 + DSCHUNK, n);
  for (int i = i0 + threadIdx.x; i < i1; i += 256) {
    int r = atomicAdd(&cnt[min(deg[i], 63)], 1);
    perm[r] = i;
  }
}

// ----------------------------- weight prep -----------------------------
__global__ __launch_bounds__(256) void k_prep(const float* __restrict__ W1l, const float* __restrict__ W1r,
                                              const float* __restrict__ W2l, const float* __restrict__ W2r,
                                              const float* __restrict__ W3l, const float* __restrict__ W3r,
                                              const float* __restrict__ Wa1, const float* __restrict__ Wa2,
                                              const float* __restrict__ Wa3,
                                              h16* __restrict__ Wc1h, h16* __restrict__ Wc2h,
                                              h16* __restrict__ Wc3h, h16* __restrict__ Wa1h,
                                              h16* __restrict__ Wa2h, h16* __restrict__ Wa3h,
                                              unsigned* __restrict__ mx) {
  int i = blockIdx.x * 256 + threadIdx.x;
  if (i < 24) mx[i] = 0u;
  if (i < 16384) {
    int k = i >> 7, j = i & 127;
    Wc1h[i] = (h16)((j < 64) ? W1l[k * 64 + j] : W1r[k * 64 + (j - 64)]);
  } else if (i < 24576) {
    int t = i - 16384;
    int k = t >> 7, j = t & 127;
    Wc2h[t] = (h16)((j < 64) ? W2l[k * 64 + j] : W2r[k * 64 + (j - 64)]);
  } else if (i < 28672) {
    int t = i - 24576;
    int k = t >> 6, j = t & 63;
    Wc3h[t] = (h16)((j < 32) ? W3l[k * 32 + j] : W3r[k * 32 + (j - 32)]);
  } else if (i < 45056) {
    int t = i - 28672;
    Wa1h[t] = (h16)Wa1[t];
  } else if (i < 61440) {
    int t = i - 45056;
    Wa2h[t] = (h16)Wa2[t];
  } else {
    int t = i - 61440;
    Wa3h[t] = (h16)Wa3[t];
  }
}

__global__ __launch_bounds__(256) void k_uprep_all(const float* __restrict__ Wa1,
                                                   const float* __restrict__ as1, const float* __restrict__ ad1,
                                                   const float* __restrict__ Wa2,
                                                   const float* __restrict__ as2, const float* __restrict__ ad2,
                                                   const float* __restrict__ Wa3,
                                                   const float* __restrict__ as3, const float* __restrict__ ad3,
                                                   float* __restrict__ us1, float* __restrict__ ud1,
                                                   float* __restrict__ us2, float* __restrict__ ud2,
                                                   float* __restrict__ us3, float* __restrict__ ud3) {
  int t = threadIdx.x;
  const float* Wa; const float* as; const float* ad; float* us; float* ud;
  int K, FOUT;
  if (blockIdx.x == 0)      { Wa = Wa1; as = as1; ad = ad1; us = us1; ud = ud1; K = 64; FOUT = 64; }
  else if (blockIdx.x == 1) { Wa = Wa2; as = as2; ad = ad2; us = us2; ud = ud2; K = 64; FOUT = 64; }
  else                      { Wa = Wa3; as = as3; ad = ad3; us = us3; ud = ud3; K = 32; FOUT = 32; }
  if (t >= 4 * K) return;
  int h = t / K, k = t % K;
  const float* wrow = Wa + (size_t)k * 4 * FOUT + h * FOUT;
  const float* asp = as + h * FOUT;
  const float* adp = ad + h * FOUT;
  float accs = 0.f, accd = 0.f;
  for (int c = 0; c < FOUT; c++) {
    float w = wrow[c];
    accs = fmaf(w, asp[c], accs);
    accd = fmaf(w, adp[c], accd);
  }
  us[h * K + k] = accs;
  ud[h * K + k] = accd;
}

// ----------------------------- MFMA GEMM (SAGE projections) -----------------------------
template <int K, bool AF32>
__global__ __launch_bounds__(256) void k_gemm(const void* __restrict__ Av,
                                              const h16* __restrict__ W,
                                              h16* __restrict__ C,
                                              int nrows, int M) {
  __shared__ h16 As[128][K + 8];
  __shared__ h16 Ws[64][K + 8];
  const int tid = threadIdx.x;
  const int wave = tid >> 6, lane = tid & 63;
  const int row0 = blockIdx.x * 128, col0 = blockIdx.y * 64;

  constexpr int AV = 128 * K / 8;
  for (int i = tid; i < AV; i += 256) {
    int r = i / (K / 8), kc = (i % (K / 8)) * 8;
    int row = row0 + r;
    h16x8 hv = {};
    if (row < nrows) {
      if constexpr (AF32) {
        const float* ap = (const float*)Av + (size_t)row * K + kc;
        float4 f0 = *(const float4*)ap;
        float4 f1 = *(const float4*)(ap + 4);
        hv = (h16x8){(h16)f0.x, (h16)f0.y, (h16)f0.z, (h16)f0.w,
                     (h16)f1.x, (h16)f1.y, (h16)f1.z, (h16)f1.w};
      } else {
        hv = *(const h16x8*)((const h16*)Av + (size_t)row * K + kc);
      }
    }
    *(h16x8*)&As[r][kc] = hv;
  }
  {
    int c = tid & 63;
    for (int k = tid >> 6; k < K; k += 4) Ws[c][k] = W[(size_t)k * M + col0 + c];
  }
  __syncthreads();

  const int fr = lane & 15;
  const int kb = (lane >> 4) * 8;
  f32x4 acc[2][4];
#pragma unroll
  for (int a = 0; a < 2; a++)
#pragma unroll
    for (int b = 0; b < 4; b++) acc[a][b] = (f32x4){0.f, 0.f, 0.f, 0.f};

#pragma unroll
  for (int k0 = 0; k0 < K; k0 += 32) {
    h16x8 af[2], bf[4];
#pragma unroll
    for (int mf = 0; mf < 2; mf++)
      af[mf] = *(const h16x8*)&As[wave * 32 + mf * 16 + fr][k0 + kb];
#pragma unroll
    for (int nf = 0; nf < 4; nf++)
      bf[nf] = *(const h16x8*)&Ws[nf * 16 + fr][k0 + kb];
#pragma unroll
    for (int mf = 0; mf < 2; mf++)
#pragma unroll
      for (int nf = 0; nf < 4; nf++)
        acc[mf][nf] = __builtin_amdgcn_mfma_f32_16x16x32_f16(af[mf], bf[nf], acc[mf][nf], 0, 0, 0);
  }

  const int rb = row0 + wave * 32 + (lane >> 4) * 4;
#pragma unroll
  for (int mf = 0; mf < 2; mf++)
#pragma unroll
    for (int reg = 0; reg < 4; reg++) {
      int row = rb + mf * 16 + reg;
      if (row < nrows) {
#pragma unroll
        for (int nf = 0; nf < 4; nf++)
          C[(size_t)row * M + col0 + nf * 16 + fr] = (h16)acc[mf][nf][reg];
      }
    }
}

// ----------------------------- per-head max over als/ald -----------------------------
__global__ __launch_bounds__(256) void k_headmax(const float* __restrict__ als,
                                                 const float* __restrict__ ald,
                                                 unsigned* __restrict__ mxs,
                                                 unsigned* __restrict__ mxd, int n) {
  float ms[4] = {-1e30f, -1e30f, -1e30f, -1e30f};
  float md[4] = {-1e30f, -1e30f, -1e30f, -1e30f};
  for (int v = blockIdx.x * 256 + threadIdx.x; v < n; v += gridDim.x * 256) {
    float4 s = ((const float4*)als)[v];
    float4 d = ((const float4*)ald)[v];
    ms[0] = fmaxf(ms[0], s.x); ms[1] = fmaxf(ms[1], s.y);
    ms[2] = fmaxf(ms[2], s.z); ms[3] = fmaxf(ms[3], s.w);
    md[0] = fmaxf(md[0], d.x); md[1] = fmaxf(md[1], d.y);
    md[2] = fmaxf(md[2], d.z); md[3] = fmaxf(md[3], d.w);
  }
#pragma unroll
  for (int j = 0; j < 4; j++)
    for (int m = 1; m < 64; m <<= 1) {
      ms[j] = fmaxf(ms[j], __shfl_xor(ms[j], m));
      md[j] = fmaxf(md[j], __shfl_xor(md[j], m));
    }
  __shared__ float shs[4][4], shd[4][4];
  int wave = threadIdx.x >> 6, lane = threadIdx.x & 63;
  if (lane == 0)
#pragma unroll
    for (int j = 0; j < 4; j++) { shs[wave][j] = ms[j]; shd[wave][j] = md[j]; }
  __syncthreads();
  if (threadIdx.x < 4) {
    int j = threadIdx.x;
    float a = fmaxf(fmaxf(shs[0][j], shs[1][j]), fmaxf(shs[2][j], shs[3][j]));
    float b = fmaxf(fmaxf(shd[0][j], shd[1][j]), fmaxf(shd[2][j], shd[3][j]));
    atomicMax(&mxs[j], fenc(a));
    atomicMax(&mxd[j], fenc(b));
  }
}

// ------------------ SAGE aggregate + fused GAT score (degree-sorted) ------------------
template <int F>
__global__ __launch_bounds__(256) void k_sage_agg(const h16* __restrict__ hcat,
                                                  const float* __restrict__ bias,
                                                  const int* __restrict__ offsets,
                                                  const int* __restrict__ csr_src,
                                                  const int* __restrict__ perm,
                                                  const float* __restrict__ u_s,
                                                  const float* __restrict__ u_d,
                                                  h16* __restrict__ out,
                                                  float* __restrict__ als,
                                                  float* __restrict__ ald, int n) {
  constexpr int LPN = F / 8;
  constexpr int NPW = 64 / LPN;
  const int wavei = threadIdx.x >> 6, lane = threadIdx.x & 63;
  const int g = lane / LPN, lr = lane % LPN;
  int vidx = (blockIdx.x * 4 + wavei) * NPW + g;
  if (vidx >= n) return;
  int v = perm[vidx];
  const int c0 = lr * 8;
  constexpr int st = 2 * F;
  int d0 = offsets[v], d1 = offsets[v + 1];
  float acc[8] = {};
  int e = d0;
  for (; e + 2 <= d1; e += 2) {
    int s0 = csr_src[e], s1 = csr_src[e + 1];
    h16x8 xa = *(const h16x8*)&hcat[(size_t)s0 * st + c0];
    h16x8 xb = *(const h16x8*)&hcat[(size_t)s1 * st + c0];
#pragma unroll
    for (int q = 0; q < 8; q++) acc[q] += (float)xa[q] + (float)xb[q];
  }
  for (; e < d1; ++e) {
    h16x8 xa = *(const h16x8*)&hcat[(size_t)csr_src[e] * st + c0];
#pragma unroll
    for (int q = 0; q < 8; q++) acc[q] += (float)xa[q];
  }
  int d = d1 - d0;
  float inv = 1.f / (float)(d > 1 ? d : 1);
  h16x8 hr = *(const h16x8*)&hcat[(size_t)v * st + F + c0];
  float4 b0 = *(const float4*)&bias[c0];
  float4 b1 = *(const float4*)&bias[c0 + 4];
  float bb[8] = {b0.x, b0.y, b0.z, b0.w, b1.x, b1.y, b1.z, b1.w};
  float y[8];
  h16x8 o;
#pragma unroll
  for (int q = 0; q < 8; q++) {
    float t = fmaf(acc[q], inv, bb[q] + (float)hr[q]);
    y[q] = fmaxf(t, 0.f);
    o[q] = (h16)y[q];
  }
  *(h16x8*)&out[(size_t)v * F + c0] = o;

  float ps[4], pd[4];
#pragma unroll
  for (int h = 0; h < 4; h++) {
    float4 us0 = *(const float4*)&u_s[h * F + c0];
    float4 us1 = *(const float4*)&u_s[h * F + c0 + 4];
    float4 ud0 = *(const float4*)&u_d[h * F + c0];
    float4 ud1 = *(const float4*)&u_d[h * F + c0 + 4];
    float uu_s[8] = {us0.x, us0.y, us0.z, us0.w, us1.x, us1.y, us1.z, us1.w};
    float uu_d[8] = {ud0.x, ud0.y, ud0.z, ud0.w, ud1.x, ud1.y, ud1.z, ud1.w};
    float as_ = 0.f, ad_ = 0.f;
#pragma unroll
    for (int q = 0; q < 8; q++) {
      as_ = fmaf(y[q], uu_s[q], as_);
      ad_ = fmaf(y[q], uu_d[q], ad_);
    }
    ps[h] = as_; pd[h] = ad_;
  }
#pragma unroll
  for (int mm = 1; mm < LPN; mm <<= 1)
#pragma unroll
    for (int h = 0; h < 4; h++) {
      ps[h] += __shfl_xor(ps[h], mm);
      pd[h] += __shfl_xor(pd[h], mm);
    }
  if (lr == 0) {
    *(float4*)&als[v * 4] = make_float4(ps[0], ps[1], ps[2], ps[3]);
    *(float4*)&ald[v * 4] = make_float4(pd[0], pd[1], pd[2], pd[3]);
  }
}

// ------------- GAT gather (degree-sorted, src-bucketed csr) -------------
template <int K>
__global__ __launch_bounds__(256) void k_gat_gather(const h16* __restrict__ x,
                                                    const float* __restrict__ als,
                                                    const float* __restrict__ ald,
                                                    const unsigned* __restrict__ mxs,
                                                    const unsigned* __restrict__ mxd,
                                                    const int* __restrict__ offsets,
                                                    const int* __restrict__ csr_src,
                                                    const int* __restrict__ perm,
                                                    h16* __restrict__ aggH, int n) {
  constexpr int LPN = K / 8;
  constexpr int NPW = 64 / LPN;
  const int wavei = threadIdx.x >> 6, lane = threadIdx.x & 63;
  const int g = lane / LPN, lr = lane % LPN;
  int vidx = (blockIdx.x * 4 + wavei) * NPW + g;
  if (vidx >= n) return;
  int v = perm[vidx];
  const int c0 = lr * 8;
  const float C2 = 1.44269504f;
  float4 ad4 = *(const float4*)&ald[v * 4];
  float adc[4], Mc[4];
#pragma unroll
  for (int h = 0; h < 4; h++) {
    adc[h] = ((const float*)&ad4)[h] * C2;
    float msum = fdec(mxs[h]) + fdec(mxd[h]);
    Mc[h] = fmaxf(msum, 0.2f * msum) * C2;
  }
  int d0 = offsets[v], d1 = offsets[v + 1];
  float S[4] = {};
  float acc[4][8] = {};

  int e = d0;
  for (; e + 2 <= d1; e += 2) {
    int s0 = csr_src[e], s1 = csr_src[e + 1];
    float4 l0 = *(const float4*)&als[(size_t)s0 * 4];
    float4 l1 = *(const float4*)&als[(size_t)s1 * 4];
    h16x8 x0 = *(const h16x8*)&x[(size_t)s0 * K + c0];
    h16x8 x1 = *(const h16x8*)&x[(size_t)s1 * K + c0];
    float w0[4], w1[4];
#pragma unroll
    for (int h = 0; h < 4; h++) {
      float u0 = fmaf(((const float*)&l0)[h], C2, adc[h]);
      u0 = fmaxf(u0, 0.2f * u0);
      w0[h] = exp2f(u0 - Mc[h]);
      S[h] += w0[h];
      float u1 = fmaf(((const float*)&l1)[h], C2, adc[h]);
      u1 = fmaxf(u1, 0.2f * u1);
      w1[h] = exp2f(u1 - Mc[h]);
      S[h] += w1[h];
    }
#pragma unroll
    for (int h = 0; h < 4; h++)
#pragma unroll
      for (int q = 0; q < 8; q++) {
        acc[h][q] = fmaf(w0[h], (float)x0[q], acc[h][q]);
        acc[h][q] = fmaf(w1[h], (float)x1[q], acc[h][q]);
      }
  }
  for (; e < d1; ++e) {
    int s = csr_src[e];
    float4 l = *(const float4*)&als[(size_t)s * 4];
    h16x8 x8 = *(const h16x8*)&x[(size_t)s * K + c0];
    float w[4];
#pragma unroll
    for (int h = 0; h < 4; h++) {
      float u = fmaf(((const float*)&l)[h], C2, adc[h]);
      u = fmaxf(u, 0.2f * u);
      w[h] = exp2f(u - Mc[h]);
      S[h] += w[h];
    }
#pragma unroll
    for (int h = 0; h < 4; h++)
#pragma unroll
      for (int q = 0; q < 8; q++) acc[h][q] = fmaf(w[h], (float)x8[q], acc[h][q]);
  }

#pragma unroll
  for (int h = 0; h < 4; h++) {
    float inv = 1.f / (S[h] + 1e-16f);
    h16x8 o;
#pragma unroll
    for (int q = 0; q < 8; q++) o[q] = (h16)(acc[h][q] * inv);
    *(h16x8*)&aggH[((size_t)v * 4 + h) * K + c0] = o;
  }
}

// ------------- head-GEMM (+optionally fused penalty/exp/L2-norm final) -------------
template <int K, int FOUT, bool FINAL>
__global__ __launch_bounds__(256) void k_headgemm(const h16* __restrict__ aggH,
                                                  const h16* __restrict__ Wa,
                                                  const float* __restrict__ ba,
                                                  h16* __restrict__ out,
                                                  const float* __restrict__ Wp,
                                                  const float* __restrict__ bp,
                                                  float* __restrict__ outf, int nrows) {
  __shared__ h16 As[128][K + 8];
  __shared__ h16 Ws[FOUT][K + 8];
  const int tid = threadIdx.x;
  const int wave = tid >> 6, lane = tid & 63;
  const int row0 = blockIdx.x * 128;
  const int fr = lane & 15;
  const int kb = (lane >> 4) * 8;
  constexpr int NF = FOUT / 16;
  const int rb = row0 + wave * 32 + (lane >> 4) * 4;

  float mean[2][NF][4] = {};

  for (int h = 0; h < 4; h++) {
    constexpr int AV = 128 * K / 8;
    for (int i = tid; i < AV; i += 256) {
      int r = i / (K / 8), kc = (i % (K / 8)) * 8;
      int row = row0 + r;
      h16x8 hv = {};
      if (row < nrows) hv = *(const h16x8*)&aggH[((size_t)row * 4 + h) * K + kc];
      *(h16x8*)&As[r][kc] = hv;
    }
    {
      int c = tid % FOUT;
      for (int k = tid / FOUT; k < K; k += 256 / FOUT)
        Ws[c][k] = Wa[(size_t)k * 4 * FOUT + h * FOUT + c];
    }
    __syncthreads();

    f32x4 acc[2][NF];
#pragma unroll
    for (int a = 0; a < 2; a++)
#pragma unroll
      for (int b = 0; b < NF; b++) acc[a][b] = (f32x4){0.f, 0.f, 0.f, 0.f};
#pragma unroll
    for (int k0 = 0; k0 < K; k0 += 32) {
      h16x8 af[2], bf[NF];
#pragma unroll
      for (int mf = 0; mf < 2; mf++)
        af[mf] = *(const h16x8*)&As[wave * 32 + mf * 16 + fr][k0 + kb];
#pragma unroll
      for (int nf = 0; nf < NF; nf++)
        bf[nf] = *(const h16x8*)&Ws[nf * 16 + fr][k0 + kb];
#pragma unroll
      for (int mf = 0; mf < 2; mf++)
#pragma unroll
        for (int nf = 0; nf < NF; nf++)
          acc[mf][nf] = __builtin_amdgcn_mfma_f32_16x16x32_f16(af[mf], bf[nf], acc[mf][nf], 0, 0, 0);
    }
#pragma unroll
    for (int nf = 0; nf < NF; nf++) {
      float bv = ba[h * FOUT + nf * 16 + fr];
#pragma unroll
      for (int mf = 0; mf < 2; mf++)
#pragma unroll
        for (int reg = 0; reg < 4; reg++)
          mean[mf][nf][reg] += 0.25f * fmaxf(acc[mf][nf][reg] + bv, 0.f);
    }
    __syncthreads();
  }

  if constexpr (FINAL) {
    // FOUT == 32, NF == 2. Row's 32 channels live across 16 fr-lanes x 2 nf.
    float wp0 = Wp[fr], wp1 = Wp[16 + fr];
    float bp0 = bp[0];
#pragma unroll
    for (int mf = 0; mf < 2; mf++)
#pragma unroll
      for (int reg = 0; reg < 4; reg++) {
        float y0 = mean[mf][0][reg], y1 = mean[mf][1][reg];
        float p = y0 * wp0 + y1 * wp1;
#pragma unroll
        for (int m = 1; m < 16; m <<= 1) p += __shfl_xor(p, m);
        p += bp0;
        float s = __expf(p);
        float x0 = y0 * s, x1 = y1 * s;
        float q = x0 * x0 + x1 * x1;
#pragma unroll
        for (int m = 1; m < 16; m <<= 1) q += __shfl_xor(q, m);
        float nrm = fmaxf(sqrtf(q), 1e-12f);
        int row = rb + mf * 16 + reg;
        if (row < nrows) {
          outf[(size_t)row * 32 + fr] = x0 / nrm;
          outf[(size_t)row * 32 + 16 + fr] = x1 / nrm;
        }
      }
  } else {
#pragma unroll
    for (int mf = 0; mf < 2; mf++)
#pragma unroll
      for (int reg = 0; reg < 4; reg++) {
        int row = rb + mf * 16 + reg;
        if (row < nrows) {
#pragma unroll
          for (int nf = 0; nf < NF; nf++)
            out[(size_t)row * FOUT + nf * 16 + fr] = (h16)mean[mf][nf][reg];
        }
      }
  }
}

// ----------------------------- launch -----------------------------
extern "C" void kernel_launch(void* const* d_in, const int* in_sizes, int n_in,
                              void* d_out, int out_size, void* d_ws, size_t ws_size,
                              hipStream_t stream) {
  (void)in_sizes; (void)n_in; (void)out_size; (void)ws_size;
  const float* x   = (const float*)d_in[0];
  const int*   ei  = (const int*)d_in[1];
  const float* W1l = (const float*)d_in[2];
  const float* b1l = (const float*)d_in[3];
  const float* W1r = (const float*)d_in[4];
  const float* Wa1 = (const float*)d_in[5];
  const float* as1 = (const float*)d_in[6];
  const float* ad1 = (const float*)d_in[7];
  const float* ba1 = (const float*)d_in[8];
  const float* W2l = (const float*)d_in[9];
  const float* b2l = (const float*)d_in[10];
  const float* W2r = (const float*)d_in[11];
  const float* Wa2 = (const float*)d_in[12];
  const float* as2 = (const float*)d_in[13];
  const float* ad2 = (const float*)d_in[14];
  const float* ba2 = (const float*)d_in[15];
  const float* W3l = (const float*)d_in[16];
  const float* b3l = (const float*)d_in[17];
  const float* W3r = (const float*)d_in[18];
  const float* Wa3 = (const float*)d_in[19];
  const float* as3 = (const float*)d_in[20];
  const float* ad3 = (const float*)d_in[21];
  const float* ba3 = (const float*)d_in[22];
  const float* Wp  = (const float*)d_in[23];
  const float* bp  = (const float*)d_in[24];
  float* out = (float*)d_out;

  char* ws = (char*)d_ws;
  size_t off = 0;
  auto alloc = [&](size_t bytes) -> void* {
    void* p = ws + off;
    off += (bytes + 255) & ~(size_t)255;
    return p;
  };
  int* deg      = (int*)alloc((size_t)NNODES * 4);
  int* offs     = (int*)alloc((size_t)(NNODES + 1) * 4);
  int* cursor   = (int*)alloc((size_t)NNODES * 4);
  int* csr      = (int*)alloc((size_t)NEDGES * 4);
  int* csr2     = (int*)alloc((size_t)NEDGES * 4);
  int* bsums    = (int*)alloc((size_t)SCAN_BLOCKS * 4);
  int* perm     = (int*)alloc((size_t)NNODES * 4);
  h16* Wc1h     = (h16*)alloc((size_t)128 * 128 * 2);
  h16* Wc2h     = (h16*)alloc((size_t)64 * 128 * 2);
  h16* Wc3h     = (h16*)alloc((size_t)64 * 64 * 2);
  h16* Wa1h     = (h16*)alloc((size_t)64 * 256 * 2);
  h16* Wa2h     = (h16*)alloc((size_t)64 * 256 * 2);
  h16* Wa3h     = (h16*)alloc((size_t)32 * 128 * 2);
  h16* aggH     = (h16*)alloc((size_t)NNODES * 256 * 2);  // [N][4][K]; aliased as hist partials
  h16* bufCD    = (h16*)alloc((size_t)NNODES * 128 * 2);  // [hl|hr]
  h16* bufB     = (h16*)alloc((size_t)NNODES * 64 * 2);   // layer io
  float* als    = (float*)alloc((size_t)NNODES * 4 * 4);
  float* ald    = (float*)alloc((size_t)NNODES * 4 * 4);
  float* us1    = (float*)alloc(4 * 64 * 4);
  float* ud1    = (float*)alloc(4 * 64 * 4);
  float* us2    = (float*)alloc(4 * 64 * 4);
  float* ud2    = (float*)alloc(4 * 64 * 4);
  float* us3    = (float*)alloc(4 * 32 * 4);
  float* ud3    = (float*)alloc(4 * 32 * 4);
  unsigned* mx  = (unsigned*)alloc(24 * 4);  // [als 3x4 | ald 3x4]

  int* part = (int*)aggH;                      // HPART * NNODES ints = 25.6 MB
  int* sc   = part + (size_t)HPART * NNODES;   // degree-sort strip counts (64*64)

  int eb = (NEDGES + 255) / 256;
  k_hist<<<dim3(HPART, HRANGES), 256, 0, stream>>>(ei + NEDGES, part, NEDGES);
  k_prep<<<256, 256, 0, stream>>>(W1l, W1r, W2l, W2r, W3l, W3r, Wa1, Wa2, Wa3,
                                  Wc1h, Wc2h, Wc3h, Wa1h, Wa2h, Wa3h, mx);
  k_uprep_all<<<3, 256, 0, stream>>>(Wa1, as1, ad1, Wa2, as2, ad2, Wa3, as3, ad3,
                                     us1, ud1, us2, ud2, us3, ud3);
  k_scan1<<<SCAN_BLOCKS, 256, 0, stream>>>(part, deg, bsums, NNODES);
  k_dsA<<<DSB, 256, 0, stream>>>(deg, sc, NNODES);
  k_dsB<<<1, 64, 0, stream>>>(sc);
  k_dsC<<<DSB, 256, 0, stream>>>(deg, sc, perm, NNODES);
  k_scan2<<<1, 128, 0, stream>>>(bsums, offs, NNODES);
  k_scan3<<<SCAN_BLOCKS, 256, 0, stream>>>(deg, bsums, offs, cursor, NNODES);
  for (int p = 0; p < FILL_PASSES; p++)
    k_fill<<<eb, 256, 0, stream>>>(ei, cursor, csr, NEDGES,
                                   p * FILL_RANGE, min((p + 1) * FILL_RANGE, NNODES));
  k_bsort<<<(NNODES + 3) / 4, 256, 0, stream>>>(offs, csr, csr2, NNODES);

  const int gx = (NNODES + 127) / 128;
  const int nb_sage64 = (NNODES + 31) / 32;   // NPW=8
  const int nb_sage32 = (NNODES + 63) / 64;   // NPW=16
  const int nb_g64    = (NNODES + 31) / 32;   // gather K=64: 8 nodes/wave
  const int nb_g32    = (NNODES + 63) / 64;   // gather K=32: 16 nodes/wave

  // ---- block 1 ----
  k_gemm<128, true><<<dim3(gx, 2), 256, 0, stream>>>(x, Wc1h, bufCD, NNODES, 128);
  k_sage_agg<64><<<nb_sage64, 256, 0, stream>>>(bufCD, b1l, offs, csr2, perm, us1, ud1, bufB, als, ald, NNODES);
  k_headmax<<<64, 256, 0, stream>>>(als, ald, mx + 0, mx + 12, NNODES);
  k_gat_gather<64><<<nb_g64, 256, 0, stream>>>(bufB, als, ald, mx + 0, mx + 12, offs, csr2, perm, aggH, NNODES);
  k_headgemm<64, 64, false><<<gx, 256, 0, stream>>>(aggH, Wa1h, ba1, bufB, nullptr, nullptr, nullptr, NNODES);

  // ---- block 2 ----
  k_gemm<64, false><<<dim3(gx, 2), 256, 0, stream>>>(bufB, Wc2h, bufCD, NNODES, 128);
  k_sage_agg<64><<<nb_sage64, 256, 0, stream>>>(bufCD, b2l, offs, csr2, perm, us2, ud2, bufB, als, ald, NNODES);
  k_headmax<<<64, 256, 0, stream>>>(als, ald, mx + 4, mx + 16, NNODES);
  k_gat_gather<64><<<nb_g64, 256, 0, stream>>>(bufB, als, ald, mx + 4, mx + 16, offs, csr2, perm, aggH, NNODES);
  k_headgemm<64, 64, false><<<gx, 256, 0, stream>>>(aggH, Wa2h, ba2, bufB, nullptr, nullptr, nullptr, NNODES);

  // ---- block 3 ----
  k_gemm<64, false><<<dim3(gx, 1), 256, 0, stream>>>(bufB, Wc3h, bufCD, NNODES, 64);
  k_sage_agg<32><<<nb_sage32, 256, 0, stream>>>(bufCD, b3l, offs, csr2, perm, us3, ud3, bufB, als, ald, NNODES);
  k_headmax<<<64, 256, 0, stream>>>(als, ald, mx + 8, mx + 20, NNODES);
  k_gat_gather<32><<<nb_g32, 256, 0, stream>>>(bufB, als, ald, mx + 8, mx + 20, offs, csr2, perm, aggH, NNODES);
  k_headgemm<32, 32, true><<<gx, 256, 0, stream>>>(aggH, Wa3h, ba3, nullptr, Wp, bp, out, NNODES);
}

// Round 16
// 598.697 us; speedup vs baseline: 1.0536x; 1.0536x over previous
//
#include <hip/hip_runtime.h>
#include <math.h>

#define NNODES 100000
#define NEDGES 1600000
#define SCAN_CHUNK 1024
#define SCAN_BLOCKS ((NNODES + SCAN_CHUNK - 1) / SCAN_CHUNK)
#define FILL_PASSES 4
#define FILL_RANGE ((NNODES + FILL_PASSES - 1) / FILL_PASSES)
#define HPART 64
#define HRANGES 8
#define HRANGE ((NNODES + HRANGES - 1) / HRANGES)
#define DSB 64
#define DSCHUNK ((NNODES + DSB - 1) / DSB)

typedef _Float16 h16;
typedef _Float16 h16x4 __attribute__((ext_vector_type(4)));
typedef _Float16 h16x8 __attribute__((ext_vector_type(8)));
typedef float f32x4 __attribute__((ext_vector_type(4)));

__device__ __forceinline__ unsigned fenc(float f) {
  unsigned u = __float_as_uint(f);
  return (u >> 31) ? ~u : (u | 0x80000000u);
}
__device__ __forceinline__ float fdec(unsigned e) {
  unsigned u = (e & 0x80000000u) ? (e & 0x7fffffffu) : ~e;
  return __uint_as_float(u);
}

// ----------------------------- CSR build -----------------------------
__global__ __launch_bounds__(256) void k_hist(const int* __restrict__ dst,
                                              int* __restrict__ part, int E) {
  __shared__ int hloc[HRANGE];
  const int lo = blockIdx.y * HRANGE;
  const int hi = min(lo + HRANGE, NNODES);
  const int len = hi - lo;
  for (int i = threadIdx.x; i < len; i += 256) hloc[i] = 0;
  __syncthreads();
  int per = (E + gridDim.x - 1) / gridDim.x;
  int e0 = blockIdx.x * per, e1 = min(e0 + per, E);
  for (int e = e0 + threadIdx.x; e < e1; e += 256) {
    int d = dst[e] - lo;
    if ((unsigned)d < (unsigned)len) atomicAdd(&hloc[d], 1);
  }
  __syncthreads();
  int* mine = part + (size_t)blockIdx.x * NNODES + lo;
  for (int i = threadIdx.x * 4; i + 3 < len; i += 1024)
    *(int4*)&mine[i] = *(const int4*)&hloc[i];
}

__global__ __launch_bounds__(256) void k_scan1(const int* __restrict__ part,
                                               int* __restrict__ deg,
                                               int* __restrict__ bsums, int n) {
  __shared__ int red[4];
  int base = blockIdx.x * SCAN_CHUNK + threadIdx.x * 4;
  int d0 = 0, d1 = 0, d2 = 0, d3 = 0;
  if (base + 3 < n) {
    for (int p = 0; p < HPART; p++) {
      int4 v = *(const int4*)&part[(size_t)p * NNODES + base];
      d0 += v.x; d1 += v.y; d2 += v.z; d3 += v.w;
    }
    *(int4*)&deg[base] = make_int4(d0, d1, d2, d3);
  } else if (base < n) {
    int dd[4] = {};
    for (int p = 0; p < HPART; p++)
      for (int j = 0; j < 4; j++)
        if (base + j < n) dd[j] += part[(size_t)p * NNODES + base + j];
    for (int j = 0; j < 4; j++)
      if (base + j < n) deg[base + j] = dd[j];
    d0 = dd[0]; d1 = dd[1]; d2 = dd[2]; d3 = dd[3];
  }
  int s = d0 + d1 + d2 + d3;
  for (int m = 1; m < 64; m <<= 1) s += __shfl_xor(s, m);
  int wave = threadIdx.x >> 6, lane = threadIdx.x & 63;
  if (lane == 0) red[wave] = s;
  __syncthreads();
  if (threadIdx.x == 0) bsums[blockIdx.x] = red[0] + red[1] + red[2] + red[3];
}

__global__ __launch_bounds__(128) void k_scan2(int* __restrict__ bsums,
                                               int* __restrict__ offsets, int n) {
  __shared__ int sh[128];
  int t = threadIdx.x;
  int v = (t < SCAN_BLOCKS) ? bsums[t] : 0;
  sh[t] = v;
  __syncthreads();
  for (int off = 1; off < 128; off <<= 1) {
    int u = (t >= off) ? sh[t - off] : 0;
    __syncthreads();
    sh[t] += u;
    __syncthreads();
  }
  if (t < SCAN_BLOCKS) bsums[t] = sh[t] - v;
  if (t == 127) offsets[n] = sh[127];
}

__global__ __launch_bounds__(256) void k_scan3(const int* __restrict__ deg,
                                               const int* __restrict__ bsums,
                                               int* __restrict__ offsets,
                                               int* __restrict__ cursor, int n) {
  __shared__ int sh[256];
  int t = threadIdx.x;
  int base = blockIdx.x * SCAN_CHUNK + t * 4;
  int d[4];
#pragma unroll
  for (int j = 0; j < 4; j++) d[j] = (base + j < n) ? deg[base + j] : 0;
  int tsum = d[0] + d[1] + d[2] + d[3];
  sh[t] = tsum;
  __syncthreads();
  for (int off = 1; off < 256; off <<= 1) {
    int u = (t >= off) ? sh[t - off] : 0;
    __syncthreads();
    sh[t] += u;
    __syncthreads();
  }
  int run = bsums[blockIdx.x] + sh[t] - tsum;
#pragma unroll
  for (int j = 0; j < 4; j++) {
    if (base + j < n) { offsets[base + j] = run; cursor[base + j] = run; }
    run += d[j];
  }
}

__global__ void k_fill(const int* __restrict__ ei, int* __restrict__ cursor,
                       int* __restrict__ csr_src, int E, int lo, int hi) {
  int e = blockIdx.x * blockDim.x + threadIdx.x;
  if (e >= E) return;
  int dst = ei[E + e];
  if (dst < lo || dst >= hi) return;
  int slot = atomicAdd(&cursor[dst], 1);
  csr_src[slot] = ei[e];
}

// ----------------------------- degree-sorted node permutation -----------------------------
__global__ __launch_bounds__(256) void k_dsA(const int* __restrict__ deg,
                                             int* __restrict__ sc, int n) {
  __shared__ int cnt[64];
  if (threadIdx.x < 64) cnt[threadIdx.x] = 0;
  __syncthreads();
  int i0 = blockIdx.x * DSCHUNK, i1 = min(i0 + DSCHUNK, n);
  for (int i = i0 + threadIdx.x; i < i1; i += 256)
    atomicAdd(&cnt[min(deg[i], 63)], 1);
  __syncthreads();
  if (threadIdx.x < 64) sc[blockIdx.x * 64 + threadIdx.x] = cnt[threadIdx.x];
}

__global__ __launch_bounds__(64) void k_dsB(int* __restrict__ sc) {
  __shared__ int tot[64];
  int k = threadIdx.x;
  int t = 0;
  for (int b = 0; b < DSB; b++) t += sc[b * 64 + k];
  tot[k] = t;
  __syncthreads();
  if (k == 0) {
    int run = 0;
    for (int j = 0; j < 64; j++) { int tt = tot[j]; tot[j] = run; run += tt; }
  }
  __syncthreads();
  int base = tot[k];
  for (int b = 0; b < DSB; b++) {
    int c = sc[b * 64 + k];
    sc[b * 64 + k] = base;
    base += c;
  }
}

__global__ __launch_bounds__(256) void k_dsC(const int* __restrict__ deg,
                                             const int* __restrict__ sc,
                                             int* __restrict__ perm, int n) {
  __shared__ int cnt[64];
  if (threadIdx.x < 64) cnt[threadIdx.x] = sc[blockIdx.x * 64 + threadIdx.x];
  __syncthreads();
  int i0 = blockIdx.x * DSCHUNK, i1 = min(i0 + DSCHUNK, n);
  for (int i = i0 + threadIdx.x; i < i1; i += 256) {
    int r = atomicAdd(&cnt[min(deg[i], 63)], 1);
    perm[r] = i;
  }
}

// ----------------------------- weight prep -----------------------------
__global__ __launch_bounds__(256) void k_prep(const float* __restrict__ W1l, const float* __restrict__ W1r,
                                              const float* __restrict__ W2l, const float* __restrict__ W2r,
                                              const float* __restrict__ W3l, const float* __restrict__ W3r,
                                              const float* __restrict__ Wa1, const float* __restrict__ Wa2,
                                              const float* __restrict__ Wa3,
                                              h16* __restrict__ Wc1h, h16* __restrict__ Wc2h,
                                              h16* __restrict__ Wc3h, h16* __restrict__ Wa1h,
                                              h16* __restrict__ Wa2h, h16* __restrict__ Wa3h,
                                              unsigned* __restrict__ mx) {
  int i = blockIdx.x * 256 + threadIdx.x;
  if (i < 24) mx[i] = 0u;
  if (i < 16384) {
    int k = i >> 7, j = i & 127;
    Wc1h[i] = (h16)((j < 64) ? W1l[k * 64 + j] : W1r[k * 64 + (j - 64)]);
  } else if (i < 24576) {
    int t = i - 16384;
    int k = t >> 7, j = t & 127;
    Wc2h[t] = (h16)((j < 64) ? W2l[k * 64 + j] : W2r[k * 64 + (j - 64)]);
  } else if (i < 28672) {
    int t = i - 24576;
    int k = t >> 6, j = t & 63;
    Wc3h[t] = (h16)((j < 32) ? W3l[k * 32 + j] : W3r[k * 32 + (j - 32)]);
  } else if (i < 45056) {
    int t = i - 28672;
    Wa1h[t] = (h16)Wa1[t];
  } else if (i < 61440) {
    int t = i - 45056;
    Wa2h[t] = (h16)Wa2[t];
  } else {
    int t = i - 61440;
    Wa3h[t] = (h16)Wa3[t];
  }
}

__global__ __launch_bounds__(256) void k_uprep_all(const float* __restrict__ Wa1,
                                                   const float* __restrict__ as1, const float* __restrict__ ad1,
                                                   const float* __restrict__ Wa2,
                                                   const float* __restrict__ as2, const float* __restrict__ ad2,
                                                   const float* __restrict__ Wa3,
                                                   const float* __restrict__ as3, const float* __restrict__ ad3,
                                                   float* __restrict__ us1, float* __restrict__ ud1,
                                                   float* __restrict__ us2, float* __restrict__ ud2,
                                                   float* __restrict__ us3, float* __restrict__ ud3) {
  int t = threadIdx.x;
  const float* Wa; const float* as; const float* ad; float* us; float* ud;
  int K, FOUT;
  if (blockIdx.x == 0)      { Wa = Wa1; as = as1; ad = ad1; us = us1; ud = ud1; K = 64; FOUT = 64; }
  else if (blockIdx.x == 1) { Wa = Wa2; as = as2; ad = ad2; us = us2; ud = ud2; K = 64; FOUT = 64; }
  else                      { Wa = Wa3; as = as3; ad = ad3; us = us3; ud = ud3; K = 32; FOUT = 32; }
  if (t >= 4 * K) return;
  int h = t / K, k = t % K;
  const float* wrow = Wa + (size_t)k * 4 * FOUT + h * FOUT;
  const float* asp = as + h * FOUT;
  const float* adp = ad + h * FOUT;
  float accs = 0.f, accd = 0.f;
  for (int c = 0; c < FOUT; c++) {
    float w = wrow[c];
    accs = fmaf(w, asp[c], accs);
    accd = fmaf(w, adp[c], accd);
  }
  us[h * K + k] = accs;
  ud[h * K + k] = accd;
}

// ----------------------------- MFMA GEMM (SAGE projections) -----------------------------
template <int K, bool AF32>
__global__ __launch_bounds__(256) void k_gemm(const void* __restrict__ Av,
                                              const h16* __restrict__ W,
                                              h16* __restrict__ C,
                                              int nrows, int M) {
  __shared__ h16 As[128][K + 8];
  __shared__ h16 Ws[64][K + 8];
  const int tid = threadIdx.x;
  const int wave = tid >> 6, lane = tid & 63;
  const int row0 = blockIdx.x * 128, col0 = blockIdx.y * 64;

  constexpr int AV = 128 * K / 8;
  for (int i = tid; i < AV; i += 256) {
    int r = i / (K / 8), kc = (i % (K / 8)) * 8;
    int row = row0 + r;
    h16x8 hv = {};
    if (row < nrows) {
      if constexpr (AF32) {
        const float* ap = (const float*)Av + (size_t)row * K + kc;
        float4 f0 = *(const float4*)ap;
        float4 f1 = *(const float4*)(ap + 4);
        hv = (h16x8){(h16)f0.x, (h16)f0.y, (h16)f0.z, (h16)f0.w,
                     (h16)f1.x, (h16)f1.y, (h16)f1.z, (h16)f1.w};
      } else {
        hv = *(const h16x8*)((const h16*)Av + (size_t)row * K + kc);
      }
    }
    *(h16x8*)&As[r][kc] = hv;
  }
  {
    int c = tid & 63;
    for (int k = tid >> 6; k < K; k += 4) Ws[c][k] = W[(size_t)k * M + col0 + c];
  }
  __syncthreads();

  const int fr = lane & 15;
  const int kb = (lane >> 4) * 8;
  f32x4 acc[2][4];
#pragma unroll
  for (int a = 0; a < 2; a++)
#pragma unroll
    for (int b = 0; b < 4; b++) acc[a][b] = (f32x4){0.f, 0.f, 0.f, 0.f};

#pragma unroll
  for (int k0 = 0; k0 < K; k0 += 32) {
    h16x8 af[2], bf[4];
#pragma unroll
    for (int mf = 0; mf < 2; mf++)
      af[mf] = *(const h16x8*)&As[wave * 32 + mf * 16 + fr][k0 + kb];
#pragma unroll
    for (int nf = 0; nf < 4; nf++)
      bf[nf] = *(const h16x8*)&Ws[nf * 16 + fr][k0 + kb];
#pragma unroll
    for (int mf = 0; mf < 2; mf++)
#pragma unroll
      for (int nf = 0; nf < 4; nf++)
        acc[mf][nf] = __builtin_amdgcn_mfma_f32_16x16x32_f16(af[mf], bf[nf], acc[mf][nf], 0, 0, 0);
  }

  const int rb = row0 + wave * 32 + (lane >> 4) * 4;
#pragma unroll
  for (int mf = 0; mf < 2; mf++)
#pragma unroll
    for (int reg = 0; reg < 4; reg++) {
      int row = rb + mf * 16 + reg;
      if (row < nrows) {
#pragma unroll
        for (int nf = 0; nf < 4; nf++)
          C[(size_t)row * M + col0 + nf * 16 + fr] = (h16)acc[mf][nf][reg];
      }
    }
}

// ----------------------------- per-head max over als/ald -----------------------------
__global__ __launch_bounds__(256) void k_headmax(const float* __restrict__ als,
                                                 const float* __restrict__ ald,
                                                 unsigned* __restrict__ mxs,
                                                 unsigned* __restrict__ mxd, int n) {
  float ms[4] = {-1e30f, -1e30f, -1e30f, -1e30f};
  float md[4] = {-1e30f, -1e30f, -1e30f, -1e30f};
  for (int v = blockIdx.x * 256 + threadIdx.x; v < n; v += gridDim.x * 256) {
    float4 s = ((const float4*)als)[v];
    float4 d = ((const float4*)ald)[v];
    ms[0] = fmaxf(ms[0], s.x); ms[1] = fmaxf(ms[1], s.y);
    ms[2] = fmaxf(ms[2], s.z); ms[3] = fmaxf(ms[3], s.w);
    md[0] = fmaxf(md[0], d.x); md[1] = fmaxf(md[1], d.y);
    md[2] = fmaxf(md[2], d.z); md[3] = fmaxf(md[3], d.w);
  }
#pragma unroll
  for (int j = 0; j < 4; j++)
    for (int m = 1; m < 64; m <<= 1) {
      ms[j] = fmaxf(ms[j], __shfl_xor(ms[j], m));
      md[j] = fmaxf(md[j], __shfl_xor(md[j], m));
    }
  __shared__ float shs[4][4], shd[4][4];
  int wave = threadIdx.x >> 6, lane = threadIdx.x & 63;
  if (lane == 0)
#pragma unroll
    for (int j = 0; j < 4; j++) { shs[wave][j] = ms[j]; shd[wave][j] = md[j]; }
  __syncthreads();
  if (threadIdx.x < 4) {
    int j = threadIdx.x;
    float a = fmaxf(fmaxf(shs[0][j], shs[1][j]), fmaxf(shs[2][j], shs[3][j]));
    float b = fmaxf(fmaxf(shd[0][j], shd[1][j]), fmaxf(shd[2][j], shd[3][j]));
    atomicMax(&mxs[j], fenc(a));
    atomicMax(&mxd[j], fenc(b));
  }
}

// ------------------ SAGE aggregate + fused GAT score (degree-sorted, strided blocks) ----------
template <int F>
__global__ __launch_bounds__(256) void k_sage_agg(const h16* __restrict__ hcat,
                                                  const float* __restrict__ bias,
                                                  const int* __restrict__ offsets,
                                                  const int* __restrict__ csr_src,
                                                  const int* __restrict__ perm,
                                                  const float* __restrict__ u_s,
                                                  const float* __restrict__ u_d,
                                                  h16* __restrict__ out,
                                                  float* __restrict__ als,
                                                  float* __restrict__ ald, int n) {
  constexpr int LPN = F / 8;
  constexpr int NPW = 64 / LPN;
  const int wavei = threadIdx.x >> 6, lane = threadIdx.x & 63;
  const int g = lane / LPN, lr = lane % LPN;
  // strided group mapping: block spans the degree spectrum (no block-duration tail)
  int grp = wavei * gridDim.x + blockIdx.x;
  int vidx = grp * NPW + g;
  if (vidx >= n) return;
  int v = perm[vidx];
  const int c0 = lr * 8;
  constexpr int st = 2 * F;
  int d0 = offsets[v], d1 = offsets[v + 1];
  float acc[8] = {};
  int e = d0;
  for (; e + 2 <= d1; e += 2) {
    int s0 = csr_src[e], s1 = csr_src[e + 1];
    h16x8 xa = *(const h16x8*)&hcat[(size_t)s0 * st + c0];
    h16x8 xb = *(const h16x8*)&hcat[(size_t)s1 * st + c0];
#pragma unroll
    for (int q = 0; q < 8; q++) acc[q] += (float)xa[q] + (float)xb[q];
  }
  for (; e < d1; ++e) {
    h16x8 xa = *(const h16x8*)&hcat[(size_t)csr_src[e] * st + c0];
#pragma unroll
    for (int q = 0; q < 8; q++) acc[q] += (float)xa[q];
  }
  int d = d1 - d0;
  float inv = 1.f / (float)(d > 1 ? d : 1);
  h16x8 hr = *(const h16x8*)&hcat[(size_t)v * st + F + c0];
  float4 b0 = *(const float4*)&bias[c0];
  float4 b1 = *(const float4*)&bias[c0 + 4];
  float bb[8] = {b0.x, b0.y, b0.z, b0.w, b1.x, b1.y, b1.z, b1.w};
  float y[8];
  h16x8 o;
#pragma unroll
  for (int q = 0; q < 8; q++) {
    float t = fmaf(acc[q], inv, bb[q] + (float)hr[q]);
    y[q] = fmaxf(t, 0.f);
    o[q] = (h16)y[q];
  }
  *(h16x8*)&out[(size_t)v * F + c0] = o;

  float ps[4], pd[4];
#pragma unroll
  for (int h = 0; h < 4; h++) {
    float4 us0 = *(const float4*)&u_s[h * F + c0];
    float4 us1 = *(const float4*)&u_s[h * F + c0 + 4];
    float4 ud0 = *(const float4*)&u_d[h * F + c0];
    float4 ud1 = *(const float4*)&u_d[h * F + c0 + 4];
    float uu_s[8] = {us0.x, us0.y, us0.z, us0.w, us1.x, us1.y, us1.z, us1.w};
    float uu_d[8] = {ud0.x, ud0.y, ud0.z, ud0.w, ud1.x, ud1.y, ud1.z, ud1.w};
    float as_ = 0.f, ad_ = 0.f;
#pragma unroll
    for (int q = 0; q < 8; q++) {
      as_ = fmaf(y[q], uu_s[q], as_);
      ad_ = fmaf(y[q], uu_d[q], ad_);
    }
    ps[h] = as_; pd[h] = ad_;
  }
#pragma unroll
  for (int mm = 1; mm < LPN; mm <<= 1)
#pragma unroll
    for (int h = 0; h < 4; h++) {
      ps[h] += __shfl_xor(ps[h], mm);
      pd[h] += __shfl_xor(pd[h], mm);
    }
  if (lr == 0) {
    *(float4*)&als[v * 4] = make_float4(ps[0], ps[1], ps[2], ps[3]);
    *(float4*)&ald[v * 4] = make_float4(pd[0], pd[1], pd[2], pd[3]);
  }
}

// ------------- GAT gather (degree-sorted, strided blocks) -------------
template <int K>
__global__ __launch_bounds__(256) void k_gat_gather(const h16* __restrict__ x,
                                                    const float* __restrict__ als,
                                                    const float* __restrict__ ald,
                                                    const unsigned* __restrict__ mxs,
                                                    const unsigned* __restrict__ mxd,
                                                    const int* __restrict__ offsets,
                                                    const int* __restrict__ csr_src,
                                                    const int* __restrict__ perm,
                                                    h16* __restrict__ aggH, int n) {
  constexpr int LPN = K / 8;
  constexpr int NPW = 64 / LPN;
  const int wavei = threadIdx.x >> 6, lane = threadIdx.x & 63;
  const int g = lane / LPN, lr = lane % LPN;
  int grp = wavei * gridDim.x + blockIdx.x;
  int vidx = grp * NPW + g;
  if (vidx >= n) return;
  int v = perm[vidx];
  const int c0 = lr * 8;
  const float C2 = 1.44269504f;
  float4 ad4 = *(const float4*)&ald[v * 4];
  float adc[4], Mc[4];
#pragma unroll
  for (int h = 0; h < 4; h++) {
    adc[h] = ((const float*)&ad4)[h] * C2;
    float msum = fdec(mxs[h]) + fdec(mxd[h]);
    Mc[h] = fmaxf(msum, 0.2f * msum) * C2;
  }
  int d0 = offsets[v], d1 = offsets[v + 1];
  float S[4] = {};
  float acc[4][8] = {};

  int e = d0;
  for (; e + 2 <= d1; e += 2) {
    int s0 = csr_src[e], s1 = csr_src[e + 1];
    float4 l0 = *(const float4*)&als[(size_t)s0 * 4];
    float4 l1 = *(const float4*)&als[(size_t)s1 * 4];
    h16x8 x0 = *(const h16x8*)&x[(size_t)s0 * K + c0];
    h16x8 x1 = *(const h16x8*)&x[(size_t)s1 * K + c0];
    float w0[4], w1[4];
#pragma unroll
    for (int h = 0; h < 4; h++) {
      float u0 = fmaf(((const float*)&l0)[h], C2, adc[h]);
      u0 = fmaxf(u0, 0.2f * u0);
      w0[h] = exp2f(u0 - Mc[h]);
      S[h] += w0[h];
      float u1 = fmaf(((const float*)&l1)[h], C2, adc[h]);
      u1 = fmaxf(u1, 0.2f * u1);
      w1[h] = exp2f(u1 - Mc[h]);
      S[h] += w1[h];
    }
#pragma unroll
    for (int h = 0; h < 4; h++)
#pragma unroll
      for (int q = 0; q < 8; q++) {
        acc[h][q] = fmaf(w0[h], (float)x0[q], acc[h][q]);
        acc[h][q] = fmaf(w1[h], (float)x1[q], acc[h][q]);
      }
  }
  for (; e < d1; ++e) {
    int s = csr_src[e];
    float4 l = *(const float4*)&als[(size_t)s * 4];
    h16x8 x8 = *(const h16x8*)&x[(size_t)s * K + c0];
    float w[4];
#pragma unroll
    for (int h = 0; h < 4; h++) {
      float u = fmaf(((const float*)&l)[h], C2, adc[h]);
      u = fmaxf(u, 0.2f * u);
      w[h] = exp2f(u - Mc[h]);
      S[h] += w[h];
    }
#pragma unroll
    for (int h = 0; h < 4; h++)
#pragma unroll
      for (int q = 0; q < 8; q++) acc[h][q] = fmaf(w[h], (float)x8[q], acc[h][q]);
  }

#pragma unroll
  for (int h = 0; h < 4; h++) {
    float inv = 1.f / (S[h] + 1e-16f);
    h16x8 o;
#pragma unroll
    for (int q = 0; q < 8; q++) o[q] = (h16)(acc[h][q] * inv);
    *(h16x8*)&aggH[((size_t)v * 4 + h) * K + c0] = o;
  }
}

// ------------- head-GEMM (+optionally fused penalty/exp/L2-norm final) -------------
template <int K, int FOUT, bool FINAL>
__global__ __launch_bounds__(256) void k_headgemm(const h16* __restrict__ aggH,
                                                  const h16* __restrict__ Wa,
                                                  const float* __restrict__ ba,
                                                  h16* __restrict__ out,
                                                  const float* __restrict__ Wp,
                                                  const float* __restrict__ bp,
                                                  float* __restrict__ outf, int nrows) {
  __shared__ h16 As[128][K + 8];
  __shared__ h16 Ws[FOUT][K + 8];
  const int tid = threadIdx.x;
  const int wave = tid >> 6, lane = tid & 63;
  const int row0 = blockIdx.x * 128;
  const int fr = lane & 15;
  const int kb = (lane >> 4) * 8;
  constexpr int NF = FOUT / 16;
  const int rb = row0 + wave * 32 + (lane >> 4) * 4;

  float mean[2][NF][4] = {};

  for (int h = 0; h < 4; h++) {
    constexpr int AV = 128 * K / 8;
    for (int i = tid; i < AV; i += 256) {
      int r = i / (K / 8), kc = (i % (K / 8)) * 8;
      int row = row0 + r;
      h16x8 hv = {};
      if (row < nrows) hv = *(const h16x8*)&aggH[((size_t)row * 4 + h) * K + kc];
      *(h16x8*)&As[r][kc] = hv;
    }
    {
      int c = tid % FOUT;
      for (int k = tid / FOUT; k < K; k += 256 / FOUT)
        Ws[c][k] = Wa[(size_t)k * 4 * FOUT + h * FOUT + c];
    }
    __syncthreads();

    f32x4 acc[2][NF];
#pragma unroll
    for (int a = 0; a < 2; a++)
#pragma unroll
      for (int b = 0; b < NF; b++) acc[a][b] = (f32x4){0.f, 0.f, 0.f, 0.f};
#pragma unroll
    for (int k0 = 0; k0 < K; k0 += 32) {
      h16x8 af[2], bf[NF];
#pragma unroll
      for (int mf = 0; mf < 2; mf++)
        af[mf] = *(const h16x8*)&As[wave * 32 + mf * 16 + fr][k0 + kb];
#pragma unroll
      for (int nf = 0; nf < NF; nf++)
        bf[nf] = *(const h16x8*)&Ws[nf * 16 + fr][k0 + kb];
#pragma unroll
      for (int mf = 0; mf < 2; mf++)
#pragma unroll
        for (int nf = 0; nf < NF; nf++)
          acc[mf][nf] = __builtin_amdgcn_mfma_f32_16x16x32_f16(af[mf], bf[nf], acc[mf][nf], 0, 0, 0);
    }
#pragma unroll
    for (int nf = 0; nf < NF; nf++) {
      float bv = ba[h * FOUT + nf * 16 + fr];
#pragma unroll
      for (int mf = 0; mf < 2; mf++)
#pragma unroll
        for (int reg = 0; reg < 4; reg++)
          mean[mf][nf][reg] += 0.25f * fmaxf(acc[mf][nf][reg] + bv, 0.f);
    }
    __syncthreads();
  }

  if constexpr (FINAL) {
    float wp0 = Wp[fr], wp1 = Wp[16 + fr];
    float bp0 = bp[0];
#pragma unroll
    for (int mf = 0; mf < 2; mf++)
#pragma unroll
      for (int reg = 0; reg < 4; reg++) {
        float y0 = mean[mf][0][reg], y1 = mean[mf][1][reg];
        float p = y0 * wp0 + y1 * wp1;
#pragma unroll
        for (int m = 1; m < 16; m <<= 1) p += __shfl_xor(p, m);
        p += bp0;
        float s = __expf(p);
        float x0 = y0 * s, x1 = y1 * s;
        float q = x0 * x0 + x1 * x1;
#pragma unroll
        for (int m = 1; m < 16; m <<= 1) q += __shfl_xor(q, m);
        float nrm = fmaxf(sqrtf(q), 1e-12f);
        int row = rb + mf * 16 + reg;
        if (row < nrows) {
          outf[(size_t)row * 32 + fr] = x0 / nrm;
          outf[(size_t)row * 32 + 16 + fr] = x1 / nrm;
        }
      }
  } else {
#pragma unroll
    for (int mf = 0; mf < 2; mf++)
#pragma unroll
      for (int reg = 0; reg < 4; reg++) {
        int row = rb + mf * 16 + reg;
        if (row < nrows) {
#pragma unroll
          for (int nf = 0; nf < NF; nf++)
            out[(size_t)row * FOUT + nf * 16 + fr] = (h16)mean[mf][nf][reg];
        }
      }
  }
}

// ----------------------------- launch -----------------------------
extern "C" void kernel_launch(void* const* d_in, const int* in_sizes, int n_in,
                              void* d_out, int out_size, void* d_ws, size_t ws_size,
                              hipStream_t stream) {
  (void)in_sizes; (void)n_in; (void)out_size; (void)ws_size;
  const float* x   = (const float*)d_in[0];
  const int*   ei  = (const int*)d_in[1];
  const float* W1l = (const float*)d_in[2];
  const float* b1l = (const float*)d_in[3];
  const float* W1r = (const float*)d_in[4];
  const float* Wa1 = (const float*)d_in[5];
  const float* as1 = (const float*)d_in[6];
  const float* ad1 = (const float*)d_in[7];
  const float* ba1 = (const float*)d_in[8];
  const float* W2l = (const float*)d_in[9];
  const float* b2l = (const float*)d_in[10];
  const float* W2r = (const float*)d_in[11];
  const float* Wa2 = (const float*)d_in[12];
  const float* as2 = (const float*)d_in[13];
  const float* ad2 = (const float*)d_in[14];
  const float* ba2 = (const float*)d_in[15];
  const float* W3l = (const float*)d_in[16];
  const float* b3l = (const float*)d_in[17];
  const float* W3r = (const float*)d_in[18];
  const float* Wa3 = (const float*)d_in[19];
  const float* as3 = (const float*)d_in[20];
  const float* ad3 = (const float*)d_in[21];
  const float* ba3 = (const float*)d_in[22];
  const float* Wp  = (const float*)d_in[23];
  const float* bp  = (const float*)d_in[24];
  float* out = (float*)d_out;

  char* ws = (char*)d_ws;
  size_t off = 0;
  auto alloc = [&](size_t bytes) -> void* {
    void* p = ws + off;
    off += (bytes + 255) & ~(size_t)255;
    return p;
  };
  int* deg      = (int*)alloc((size_t)NNODES * 4);
  int* offs     = (int*)alloc((size_t)(NNODES + 1) * 4);
  int* cursor   = (int*)alloc((size_t)NNODES * 4);
  int* csr      = (int*)alloc((size_t)NEDGES * 4);
  int* bsums    = (int*)alloc((size_t)SCAN_BLOCKS * 4);
  int* perm     = (int*)alloc((size_t)NNODES * 4);
  h16* Wc1h     = (h16*)alloc((size_t)128 * 128 * 2);
  h16* Wc2h     = (h16*)alloc((size_t)64 * 128 * 2);
  h16* Wc3h     = (h16*)alloc((size_t)64 * 64 * 2);
  h16* Wa1h     = (h16*)alloc((size_t)64 * 256 * 2);
  h16* Wa2h     = (h16*)alloc((size_t)64 * 256 * 2);
  h16* Wa3h     = (h16*)alloc((size_t)32 * 128 * 2);
  h16* aggH     = (h16*)alloc((size_t)NNODES * 256 * 2);  // [N][4][K]; aliased as hist partials
  h16* bufCD    = (h16*)alloc((size_t)NNODES * 128 * 2);  // [hl|hr]
  h16* bufB     = (h16*)alloc((size_t)NNODES * 64 * 2);   // layer io
  float* als    = (float*)alloc((size_t)NNODES * 4 * 4);
  float* ald    = (float*)alloc((size_t)NNODES * 4 * 4);
  float* us1    = (float*)alloc(4 * 64 * 4);
  float* ud1    = (float*)alloc(4 * 64 * 4);
  float* us2    = (float*)alloc(4 * 64 * 4);
  float* ud2    = (float*)alloc(4 * 64 * 4);
  float* us3    = (float*)alloc(4 * 32 * 4);
  float* ud3    = (float*)alloc(4 * 32 * 4);
  unsigned* mx  = (unsigned*)alloc(24 * 4);  // [als 3x4 | ald 3x4]

  int* part = (int*)aggH;                      // HPART * NNODES ints = 25.6 MB
  int* sc   = part + (size_t)HPART * NNODES;   // degree-sort strip counts (64*64)

  int eb = (NEDGES + 255) / 256;
  k_hist<<<dim3(HPART, HRANGES), 256, 0, stream>>>(ei + NEDGES, part, NEDGES);
  k_prep<<<256, 256, 0, stream>>>(W1l, W1r, W2l, W2r, W3l, W3r, Wa1, Wa2, Wa3,
                                  Wc1h, Wc2h, Wc3h, Wa1h, Wa2h, Wa3h, mx);
  k_uprep_all<<<3, 256, 0, stream>>>(Wa1, as1, ad1, Wa2, as2, ad2, Wa3, as3, ad3,
                                     us1, ud1, us2, ud2, us3, ud3);
  k_scan1<<<SCAN_BLOCKS, 256, 0, stream>>>(part, deg, bsums, NNODES);
  k_dsA<<<DSB, 256, 0, stream>>>(deg, sc, NNODES);
  k_dsB<<<1, 64, 0, stream>>>(sc);
  k_dsC<<<DSB, 256, 0, stream>>>(deg, sc, perm, NNODES);
  k_scan2<<<1, 128, 0, stream>>>(bsums, offs, NNODES);
  k_scan3<<<SCAN_BLOCKS, 256, 0, stream>>>(deg, bsums, offs, cursor, NNODES);
  for (int p = 0; p < FILL_PASSES; p++)
    k_fill<<<eb, 256, 0, stream>>>(ei, cursor, csr, NEDGES,
                                   p * FILL_RANGE, min((p + 1) * FILL_RANGE, NNODES));

  const int gx = (NNODES + 127) / 128;
  const int nb_sage64 = (NNODES + 31) / 32;   // 8 nodes/wave, 4 waves
  const int nb_sage32 = (NNODES + 63) / 64;
  const int nb_g64    = (NNODES + 31) / 32;
  const int nb_g32    = (NNODES + 63) / 64;

  // ---- block 1 ----
  k_gemm<128, true><<<dim3(gx, 2), 256, 0, stream>>>(x, Wc1h, bufCD, NNODES, 128);
  k_sage_agg<64><<<nb_sage64, 256, 0, stream>>>(bufCD, b1l, offs, csr, perm, us1, ud1, bufB, als, ald, NNODES);
  k_headmax<<<64, 256, 0, stream>>>(als, ald, mx + 0, mx + 12, NNODES);
  k_gat_gather<64><<<nb_g64, 256, 0, stream>>>(bufB, als, ald, mx + 0, mx + 12, offs, csr, perm, aggH, NNODES);
  k_headgemm<64, 64, false><<<gx, 256, 0, stream>>>(aggH, Wa1h, ba1, bufB, nullptr, nullptr, nullptr, NNODES);

  // ---- block 2 ----
  k_gemm<64, false><<<dim3(gx, 2), 256, 0, stream>>>(bufB, Wc2h, bufCD, NNODES, 128);
  k_sage_agg<64><<<nb_sage64, 256, 0, stream>>>(bufCD, b2l, offs, csr, perm, us2, ud2, bufB, als, ald, NNODES);
  k_headmax<<<64, 256, 0, stream>>>(als, ald, mx + 4, mx + 16, NNODES);
  k_gat_gather<64><<<nb_g64, 256, 0, stream>>>(bufB, als, ald, mx + 4, mx + 16, offs, csr, perm, aggH, NNODES);
  k_headgemm<64, 64, false><<<gx, 256, 0, stream>>>(aggH, Wa2h, ba2, bufB, nullptr, nullptr, nullptr, NNODES);

  // ---- block 3 ----
  k_gemm<64, false><<<dim3(gx, 1), 256, 0, stream>>>(bufB, Wc3h, bufCD, NNODES, 64);
  k_sage_agg<32><<<nb_sage32, 256, 0, stream>>>(bufCD, b3l, offs, csr, perm, us3, ud3, bufB, als, ald, NNODES);
  k_headmax<<<64, 256, 0, stream>>>(als, ald, mx + 8, mx + 20, NNODES);
  k_gat_gather<32><<<nb_g32, 256, 0, stream>>>(bufB, als, ald, mx + 8, mx + 20, offs, csr, perm, aggH, NNODES);
  k_headgemm<32, 32, true><<<gx, 256, 0, stream>>>(aggH, Wa3h, ba3, nullptr, Wp, bp, out, NNODES);
}

// Round 17
// 586.674 us; speedup vs baseline: 1.0752x; 1.0205x over previous
//
#include <hip/hip_runtime.h>
#include <math.h>

#define NNODES 100000
#define NEDGES 1600000
#define SCAN_CHUNK 1024
#define SCAN_BLOCKS ((NNODES + SCAN_CHUNK - 1) / SCAN_CHUNK)
#define FILL_PASSES 4
#define FILL_RANGE ((NNODES + FILL_PASSES - 1) / FILL_PASSES)
#define HPART 64
#define HRANGES 8
#define HRANGE ((NNODES + HRANGES - 1) / HRANGES)
#define DSB 64
#define DSCHUNK ((NNODES + DSB - 1) / DSB)

typedef _Float16 h16;
typedef _Float16 h16x4 __attribute__((ext_vector_type(4)));
typedef _Float16 h16x8 __attribute__((ext_vector_type(8)));
typedef float f32x4 __attribute__((ext_vector_type(4)));

__device__ __forceinline__ unsigned fenc(float f) {
  unsigned u = __float_as_uint(f);
  return (u >> 31) ? ~u : (u | 0x80000000u);
}
__device__ __forceinline__ float fdec(unsigned e) {
  unsigned u = (e & 0x80000000u) ? (e & 0x7fffffffu) : ~e;
  return __uint_as_float(u);
}

// ----------------------------- CSR build -----------------------------
__global__ __launch_bounds__(256) void k_hist(const int* __restrict__ dst,
                                              int* __restrict__ part, int E) {
  __shared__ int hloc[HRANGE];
  const int lo = blockIdx.y * HRANGE;
  const int hi = min(lo + HRANGE, NNODES);
  const int len = hi - lo;
  for (int i = threadIdx.x; i < len; i += 256) hloc[i] = 0;
  __syncthreads();
  int per = (E + gridDim.x - 1) / gridDim.x;
  int e0 = blockIdx.x * per, e1 = min(e0 + per, E);
  for (int e = e0 + threadIdx.x; e < e1; e += 256) {
    int d = dst[e] - lo;
    if ((unsigned)d < (unsigned)len) atomicAdd(&hloc[d], 1);
  }
  __syncthreads();
  int* mine = part + (size_t)blockIdx.x * NNODES + lo;
  for (int i = threadIdx.x * 4; i + 3 < len; i += 1024)
    *(int4*)&mine[i] = *(const int4*)&hloc[i];
}

__global__ __launch_bounds__(256) void k_scan1(const int* __restrict__ part,
                                               int* __restrict__ deg,
                                               int* __restrict__ bsums, int n) {
  __shared__ int red[4];
  int base = blockIdx.x * SCAN_CHUNK + threadIdx.x * 4;
  int d0 = 0, d1 = 0, d2 = 0, d3 = 0;
  if (base + 3 < n) {
    for (int p = 0; p < HPART; p++) {
      int4 v = *(const int4*)&part[(size_t)p * NNODES + base];
      d0 += v.x; d1 += v.y; d2 += v.z; d3 += v.w;
    }
    *(int4*)&deg[base] = make_int4(d0, d1, d2, d3);
  } else if (base < n) {
    int dd[4] = {};
    for (int p = 0; p < HPART; p++)
      for (int j = 0; j < 4; j++)
        if (base + j < n) dd[j] += part[(size_t)p * NNODES + base + j];
    for (int j = 0; j < 4; j++)
      if (base + j < n) deg[base + j] = dd[j];
    d0 = dd[0]; d1 = dd[1]; d2 = dd[2]; d3 = dd[3];
  }
  int s = d0 + d1 + d2 + d3;
  for (int m = 1; m < 64; m <<= 1) s += __shfl_xor(s, m);
  int wave = threadIdx.x >> 6, lane = threadIdx.x & 63;
  if (lane == 0) red[wave] = s;
  __syncthreads();
  if (threadIdx.x == 0) bsums[blockIdx.x] = red[0] + red[1] + red[2] + red[3];
}

__global__ __launch_bounds__(128) void k_scan2(int* __restrict__ bsums,
                                               int* __restrict__ offsets, int n) {
  __shared__ int sh[128];
  int t = threadIdx.x;
  int v = (t < SCAN_BLOCKS) ? bsums[t] : 0;
  sh[t] = v;
  __syncthreads();
  for (int off = 1; off < 128; off <<= 1) {
    int u = (t >= off) ? sh[t - off] : 0;
    __syncthreads();
    sh[t] += u;
    __syncthreads();
  }
  if (t < SCAN_BLOCKS) bsums[t] = sh[t] - v;
  if (t == 127) offsets[n] = sh[127];
}

__global__ __launch_bounds__(256) void k_scan3(const int* __restrict__ deg,
                                               const int* __restrict__ bsums,
                                               int* __restrict__ offsets,
                                               int* __restrict__ cursor, int n) {
  __shared__ int sh[256];
  int t = threadIdx.x;
  int base = blockIdx.x * SCAN_CHUNK + t * 4;
  int d[4];
#pragma unroll
  for (int j = 0; j < 4; j++) d[j] = (base + j < n) ? deg[base + j] : 0;
  int tsum = d[0] + d[1] + d[2] + d[3];
  sh[t] = tsum;
  __syncthreads();
  for (int off = 1; off < 256; off <<= 1) {
    int u = (t >= off) ? sh[t - off] : 0;
    __syncthreads();
    sh[t] += u;
    __syncthreads();
  }
  int run = bsums[blockIdx.x] + sh[t] - tsum;
#pragma unroll
  for (int j = 0; j < 4; j++) {
    if (base + j < n) { offsets[base + j] = run; cursor[base + j] = run; }
    run += d[j];
  }
}

__global__ void k_fill(const int* __restrict__ ei, int* __restrict__ cursor,
                       int* __restrict__ csr_src, int E, int lo, int hi) {
  int e = blockIdx.x * blockDim.x + threadIdx.x;
  if (e >= E) return;
  int dst = ei[E + e];
  if (dst < lo || dst >= hi) return;
  int slot = atomicAdd(&cursor[dst], 1);
  csr_src[slot] = ei[e];
}

// ----------------------------- degree-sorted node permutation -----------------------------
__global__ __launch_bounds__(256) void k_dsA(const int* __restrict__ deg,
                                             int* __restrict__ sc, int n) {
  __shared__ int cnt[64];
  if (threadIdx.x < 64) cnt[threadIdx.x] = 0;
  __syncthreads();
  int i0 = blockIdx.x * DSCHUNK, i1 = min(i0 + DSCHUNK, n);
  for (int i = i0 + threadIdx.x; i < i1; i += 256)
    atomicAdd(&cnt[min(deg[i], 63)], 1);
  __syncthreads();
  if (threadIdx.x < 64) sc[blockIdx.x * 64 + threadIdx.x] = cnt[threadIdx.x];
}

__global__ __launch_bounds__(64) void k_dsB(int* __restrict__ sc) {
  __shared__ int tot[64];
  int k = threadIdx.x;
  int t = 0;
  for (int b = 0; b < DSB; b++) t += sc[b * 64 + k];
  tot[k] = t;
  __syncthreads();
  if (k == 0) {
    int run = 0;
    for (int j = 0; j < 64; j++) { int tt = tot[j]; tot[j] = run; run += tt; }
  }
  __syncthreads();
  int base = tot[k];
  for (int b = 0; b < DSB; b++) {
    int c = sc[b * 64 + k];
    sc[b * 64 + k] = base;
    base += c;
  }
}

__global__ __launch_bounds__(256) void k_dsC(const int* __restrict__ deg,
                                             const int* __restrict__ sc,
                                             int* __restrict__ perm, int n) {
  __shared__ int cnt[64];
  if (threadIdx.x < 64) cnt[threadIdx.x] = sc[blockIdx.x * 64 + threadIdx.x];
  __syncthreads();
  int i0 = blockIdx.x * DSCHUNK, i1 = min(i0 + DSCHUNK, n);
  for (int i = i0 + threadIdx.x; i < i1; i += 256) {
    int r = atomicAdd(&cnt[min(deg[i], 63)], 1);
    perm[r] = i;
  }
}

// ----------------------------- weight prep -----------------------------
__global__ __launch_bounds__(256) void k_prep(const float* __restrict__ W1l, const float* __restrict__ W1r,
                                              const float* __restrict__ W2l, const float* __restrict__ W2r,
                                              const float* __restrict__ W3l, const float* __restrict__ W3r,
                                              const float* __restrict__ Wa1, const float* __restrict__ Wa2,
                                              const float* __restrict__ Wa3,
                                              h16* __restrict__ Wc1h, h16* __restrict__ Wc2h,
                                              h16* __restrict__ Wc3h, h16* __restrict__ Wa1h,
                                              h16* __restrict__ Wa2h, h16* __restrict__ Wa3h,
                                              unsigned* __restrict__ mx) {
  int i = blockIdx.x * 256 + threadIdx.x;
  if (i < 24) mx[i] = 0u;
  if (i < 16384) {
    int k = i >> 7, j = i & 127;
    Wc1h[i] = (h16)((j < 64) ? W1l[k * 64 + j] : W1r[k * 64 + (j - 64)]);
  } else if (i < 24576) {
    int t = i - 16384;
    int k = t >> 7, j = t & 127;
    Wc2h[t] = (h16)((j < 64) ? W2l[k * 64 + j] : W2r[k * 64 + (j - 64)]);
  } else if (i < 28672) {
    int t = i - 24576;
    int k = t >> 6, j = t & 63;
    Wc3h[t] = (h16)((j < 32) ? W3l[k * 32 + j] : W3r[k * 32 + (j - 32)]);
  } else if (i < 45056) {
    int t = i - 28672;
    Wa1h[t] = (h16)Wa1[t];
  } else if (i < 61440) {
    int t = i - 45056;
    Wa2h[t] = (h16)Wa2[t];
  } else {
    int t = i - 61440;
    Wa3h[t] = (h16)Wa3[t];
  }
}

__global__ __launch_bounds__(256) void k_uprep_all(const float* __restrict__ Wa1,
                                                   const float* __restrict__ as1, const float* __restrict__ ad1,
                                                   const float* __restrict__ Wa2,
                                                   const float* __restrict__ as2, const float* __restrict__ ad2,
                                                   const float* __restrict__ Wa3,
                                                   const float* __restrict__ as3, const float* __restrict__ ad3,
                                                   float* __restrict__ us1, float* __restrict__ ud1,
                                                   float* __restrict__ us2, float* __restrict__ ud2,
                                                   float* __restrict__ us3, float* __restrict__ ud3) {
  int t = threadIdx.x;
  const float* Wa; const float* as; const float* ad; float* us; float* ud;
  int K, FOUT;
  if (blockIdx.x == 0)      { Wa = Wa1; as = as1; ad = ad1; us = us1; ud = ud1; K = 64; FOUT = 64; }
  else if (blockIdx.x == 1) { Wa = Wa2; as = as2; ad = ad2; us = us2; ud = ud2; K = 64; FOUT = 64; }
  else                      { Wa = Wa3; as = as3; ad = ad3; us = us3; ud = ud3; K = 32; FOUT = 32; }
  if (t >= 4 * K) return;
  int h = t / K, k = t % K;
  const float* wrow = Wa + (size_t)k * 4 * FOUT + h * FOUT;
  const float* asp = as + h * FOUT;
  const float* adp = ad + h * FOUT;
  float accs = 0.f, accd = 0.f;
  for (int c = 0; c < FOUT; c++) {
    float w = wrow[c];
    accs = fmaf(w, asp[c], accs);
    accd = fmaf(w, adp[c], accd);
  }
  us[h * K + k] = accs;
  ud[h * K + k] = accd;
}

// ----------------------------- MFMA GEMM (SAGE projections) -----------------------------
template <int K, bool AF32>
__global__ __launch_bounds__(256) void k_gemm(const void* __restrict__ Av,
                                              const h16* __restrict__ W,
                                              h16* __restrict__ C,
                                              int nrows, int M) {
  __shared__ h16 As[128][K + 8];
  __shared__ h16 Ws[64][K + 8];
  const int tid = threadIdx.x;
  const int wave = tid >> 6, lane = tid & 63;
  const int row0 = blockIdx.x * 128, col0 = blockIdx.y * 64;

  constexpr int AV = 128 * K / 8;
  for (int i = tid; i < AV; i += 256) {
    int r = i / (K / 8), kc = (i % (K / 8)) * 8;
    int row = row0 + r;
    h16x8 hv = {};
    if (row < nrows) {
      if constexpr (AF32) {
        const float* ap = (const float*)Av + (size_t)row * K + kc;
        float4 f0 = *(const float4*)ap;
        float4 f1 = *(const float4*)(ap + 4);
        hv = (h16x8){(h16)f0.x, (h16)f0.y, (h16)f0.z, (h16)f0.w,
                     (h16)f1.x, (h16)f1.y, (h16)f1.z, (h16)f1.w};
      } else {
        hv = *(const h16x8*)((const h16*)Av + (size_t)row * K + kc);
      }
    }
    *(h16x8*)&As[r][kc] = hv;
  }
  {
    int c = tid & 63;
    for (int k = tid >> 6; k < K; k += 4) Ws[c][k] = W[(size_t)k * M + col0 + c];
  }
  __syncthreads();

  const int fr = lane & 15;
  const int kb = (lane >> 4) * 8;
  f32x4 acc[2][4];
#pragma unroll
  for (int a = 0; a < 2; a++)
#pragma unroll
    for (int b = 0; b < 4; b++) acc[a][b] = (f32x4){0.f, 0.f, 0.f, 0.f};

#pragma unroll
  for (int k0 = 0; k0 < K; k0 += 32) {
    h16x8 af[2], bf[4];
#pragma unroll
    for (int mf = 0; mf < 2; mf++)
      af[mf] = *(const h16x8*)&As[wave * 32 + mf * 16 + fr][k0 + kb];
#pragma unroll
    for (int nf = 0; nf < 4; nf++)
      bf[nf] = *(const h16x8*)&Ws[nf * 16 + fr][k0 + kb];
#pragma unroll
    for (int mf = 0; mf < 2; mf++)
#pragma unroll
      for (int nf = 0; nf < 4; nf++)
        acc[mf][nf] = __builtin_amdgcn_mfma_f32_16x16x32_f16(af[mf], bf[nf], acc[mf][nf], 0, 0, 0);
  }

  const int rb = row0 + wave * 32 + (lane >> 4) * 4;
#pragma unroll
  for (int mf = 0; mf < 2; mf++)
#pragma unroll
    for (int reg = 0; reg < 4; reg++) {
      int row = rb + mf * 16 + reg;
      if (row < nrows) {
#pragma unroll
        for (int nf = 0; nf < 4; nf++)
          C[(size_t)row * M + col0 + nf * 16 + fr] = (h16)acc[mf][nf][reg];
      }
    }
}

// ----------------------------- per-head max over als/ald -----------------------------
__global__ __launch_bounds__(256) void k_headmax(const float* __restrict__ als,
                                                 const float* __restrict__ ald,
                                                 unsigned* __restrict__ mxs,
                                                 unsigned* __restrict__ mxd, int n) {
  float ms[4] = {-1e30f, -1e30f, -1e30f, -1e30f};
  float md[4] = {-1e30f, -1e30f, -1e30f, -1e30f};
  for (int v = blockIdx.x * 256 + threadIdx.x; v < n; v += gridDim.x * 256) {
    float4 s = ((const float4*)als)[v];
    float4 d = ((const float4*)ald)[v];
    ms[0] = fmaxf(ms[0], s.x); ms[1] = fmaxf(ms[1], s.y);
    ms[2] = fmaxf(ms[2], s.z); ms[3] = fmaxf(ms[3], s.w);
    md[0] = fmaxf(md[0], d.x); md[1] = fmaxf(md[1], d.y);
    md[2] = fmaxf(md[2], d.z); md[3] = fmaxf(md[3], d.w);
  }
#pragma unroll
  for (int j = 0; j < 4; j++)
    for (int m = 1; m < 64; m <<= 1) {
      ms[j] = fmaxf(ms[j], __shfl_xor(ms[j], m));
      md[j] = fmaxf(md[j], __shfl_xor(md[j], m));
    }
  __shared__ float shs[4][4], shd[4][4];
  int wave = threadIdx.x >> 6, lane = threadIdx.x & 63;
  if (lane == 0)
#pragma unroll
    for (int j = 0; j < 4; j++) { shs[wave][j] = ms[j]; shd[wave][j] = md[j]; }
  __syncthreads();
  if (threadIdx.x < 4) {
    int j = threadIdx.x;
    float a = fmaxf(fmaxf(shs[0][j], shs[1][j]), fmaxf(shs[2][j], shs[3][j]));
    float b = fmaxf(fmaxf(shd[0][j], shd[1][j]), fmaxf(shd[2][j], shd[3][j]));
    atomicMax(&mxs[j], fenc(a));
    atomicMax(&mxd[j], fenc(b));
  }
}

// ------------------ SAGE aggregate + fused GAT score (degree-sorted) ------------------
template <int F>
__global__ __launch_bounds__(256) void k_sage_agg(const h16* __restrict__ hcat,
                                                  const float* __restrict__ bias,
                                                  const int* __restrict__ offsets,
                                                  const int* __restrict__ csr_src,
                                                  const int* __restrict__ perm,
                                                  const float* __restrict__ u_s,
                                                  const float* __restrict__ u_d,
                                                  h16* __restrict__ out,
                                                  float* __restrict__ als,
                                                  float* __restrict__ ald, int n) {
  constexpr int LPN = F / 8;
  constexpr int NPW = 64 / LPN;
  const int wavei = threadIdx.x >> 6, lane = threadIdx.x & 63;
  const int g = lane / LPN, lr = lane % LPN;
  int vidx = (blockIdx.x * 4 + wavei) * NPW + g;
  if (vidx >= n) return;
  int v = perm[vidx];
  const int c0 = lr * 8;
  constexpr int st = 2 * F;
  int d0 = offsets[v], d1 = offsets[v + 1];
  float acc[8] = {};
  int e = d0;
  for (; e + 2 <= d1; e += 2) {
    int s0 = csr_src[e], s1 = csr_src[e + 1];
    h16x8 xa = *(const h16x8*)&hcat[(size_t)s0 * st + c0];
    h16x8 xb = *(const h16x8*)&hcat[(size_t)s1 * st + c0];
#pragma unroll
    for (int q = 0; q < 8; q++) acc[q] += (float)xa[q] + (float)xb[q];
  }
  for (; e < d1; ++e) {
    h16x8 xa = *(const h16x8*)&hcat[(size_t)csr_src[e] * st + c0];
#pragma unroll
    for (int q = 0; q < 8; q++) acc[q] += (float)xa[q];
  }
  int d = d1 - d0;
  float inv = 1.f / (float)(d > 1 ? d : 1);
  h16x8 hr = *(const h16x8*)&hcat[(size_t)v * st + F + c0];
  float4 b0 = *(const float4*)&bias[c0];
  float4 b1 = *(const float4*)&bias[c0 + 4];
  float bb[8] = {b0.x, b0.y, b0.z, b0.w, b1.x, b1.y, b1.z, b1.w};
  float y[8];
  h16x8 o;
#pragma unroll
  for (int q = 0; q < 8; q++) {
    float t = fmaf(acc[q], inv, bb[q] + (float)hr[q]);
    y[q] = fmaxf(t, 0.f);
    o[q] = (h16)y[q];
  }
  *(h16x8*)&out[(size_t)v * F + c0] = o;

  float ps[4], pd[4];
#pragma unroll
  for (int h = 0; h < 4; h++) {
    float4 us0 = *(const float4*)&u_s[h * F + c0];
    float4 us1 = *(const float4*)&u_s[h * F + c0 + 4];
    float4 ud0 = *(const float4*)&u_d[h * F + c0];
    float4 ud1 = *(const float4*)&u_d[h * F + c0 + 4];
    float uu_s[8] = {us0.x, us0.y, us0.z, us0.w, us1.x, us1.y, us1.z, us1.w};
    float uu_d[8] = {ud0.x, ud0.y, ud0.z, ud0.w, ud1.x, ud1.y, ud1.z, ud1.w};
    float as_ = 0.f, ad_ = 0.f;
#pragma unroll
    for (int q = 0; q < 8; q++) {
      as_ = fmaf(y[q], uu_s[q], as_);
      ad_ = fmaf(y[q], uu_d[q], ad_);
    }
    ps[h] = as_; pd[h] = ad_;
  }
#pragma unroll
  for (int mm = 1; mm < LPN; mm <<= 1)
#pragma unroll
    for (int h = 0; h < 4; h++) {
      ps[h] += __shfl_xor(ps[h], mm);
      pd[h] += __shfl_xor(pd[h], mm);
    }
  if (lr == 0) {
    *(float4*)&als[v * 4] = make_float4(ps[0], ps[1], ps[2], ps[3]);
    *(float4*)&ald[v * 4] = make_float4(pd[0], pd[1], pd[2], pd[3]);
  }
}

// ------------- GAT gather: cooperative per-edge weights (shfl broadcast) -------------
template <int K>
__global__ __launch_bounds__(256) void k_gat_gather(const h16* __restrict__ x,
                                                    const float* __restrict__ als,
                                                    const float* __restrict__ ald,
                                                    const unsigned* __restrict__ mxs,
                                                    const unsigned* __restrict__ mxd,
                                                    const int* __restrict__ offsets,
                                                    const int* __restrict__ csr_src,
                                                    const int* __restrict__ perm,
                                                    h16* __restrict__ aggH, int n) {
  constexpr int LPN = K / 8;
  constexpr int NPW = 64 / LPN;
  const int wavei = threadIdx.x >> 6, lane = threadIdx.x & 63;
  const int g = lane / LPN, lr = lane % LPN;
  int vidx = (blockIdx.x * 4 + wavei) * NPW + g;
  if (vidx >= n) return;
  int v = perm[vidx];
  const int c0 = lr * 8;
  const int lbase = g * LPN;
  const float C2 = 1.44269504f;
  float4 ad4 = *(const float4*)&ald[v * 4];
  float adc[4], Mc[4];
#pragma unroll
  for (int h = 0; h < 4; h++) {
    adc[h] = ((const float*)&ad4)[h] * C2;
    float msum = fdec(mxs[h]) + fdec(mxd[h]);
    Mc[h] = fmaxf(msum, 0.2f * msum) * C2;
  }
  int d0 = offsets[v], d1 = offsets[v + 1];
  float Sp[4] = {};          // per-lane partial sum (own edges only)
  float acc[4][8] = {};

  int e0 = d0;
  // full batches of LPN edges: lane lr owns edge e0+lr's weights, broadcast via shfl
  for (; e0 + LPN <= d1; e0 += LPN) {
    int s_own = csr_src[e0 + lr];
    float4 l = *(const float4*)&als[(size_t)s_own * 4];
    float w[4];
#pragma unroll
    for (int h = 0; h < 4; h++) {
      float u = fmaf(((const float*)&l)[h], C2, adc[h]);
      u = fmaxf(u, 0.2f * u);
      w[h] = exp2f(u - Mc[h]);
      Sp[h] += w[h];
    }
#pragma unroll
    for (int j = 0; j < LPN; j++) {
      int sj = __shfl(s_own, lbase + j);
      float wj[4];
#pragma unroll
      for (int h = 0; h < 4; h++) wj[h] = __shfl(w[h], lbase + j);
      h16x8 xr = *(const h16x8*)&x[(size_t)sj * K + c0];
#pragma unroll
      for (int h = 0; h < 4; h++)
#pragma unroll
        for (int q = 0; q < 8; q++) acc[h][q] = fmaf(wj[h], (float)xr[q], acc[h][q]);
    }
  }
  // tail (group-uniform count)
  if (e0 < d1) {
    int e = e0 + lr;
    bool valid = e < d1;
    int s_own = valid ? csr_src[e] : 0;
    float4 l = *(const float4*)&als[(size_t)s_own * 4];
    float w[4];
#pragma unroll
    for (int h = 0; h < 4; h++) {
      float u = fmaf(((const float*)&l)[h], C2, adc[h]);
      u = fmaxf(u, 0.2f * u);
      w[h] = exp2f(u - Mc[h]);
      if (valid) Sp[h] += w[h];
    }
    int cnt = d1 - e0;
    for (int j = 0; j < cnt; j++) {
      int sj = __shfl(s_own, lbase + j);
      float wj[4];
#pragma unroll
      for (int h = 0; h < 4; h++) wj[h] = __shfl(w[h], lbase + j);
      h16x8 xr = *(const h16x8*)&x[(size_t)sj * K + c0];
#pragma unroll
      for (int h = 0; h < 4; h++)
#pragma unroll
        for (int q = 0; q < 8; q++) acc[h][q] = fmaf(wj[h], (float)xr[q], acc[h][q]);
    }
  }

  // group-reduce softmax denominators (xor masks < LPN stay within group)
#pragma unroll
  for (int mm = 1; mm < LPN; mm <<= 1)
#pragma unroll
    for (int h = 0; h < 4; h++) Sp[h] += __shfl_xor(Sp[h], mm);

#pragma unroll
  for (int h = 0; h < 4; h++) {
    float inv = 1.f / (Sp[h] + 1e-16f);
    h16x8 o;
#pragma unroll
    for (int q = 0; q < 8; q++) o[q] = (h16)(acc[h][q] * inv);
    *(h16x8*)&aggH[((size_t)v * 4 + h) * K + c0] = o;
  }
}

// ------------- head-GEMM (+optionally fused penalty/exp/L2-norm final) -------------
template <int K, int FOUT, bool FINAL>
__global__ __launch_bounds__(256) void k_headgemm(const h16* __restrict__ aggH,
                                                  const h16* __restrict__ Wa,
                                                  const float* __restrict__ ba,
                                                  h16* __restrict__ out,
                                                  const float* __restrict__ Wp,
                                                  const float* __restrict__ bp,
                                                  float* __restrict__ outf, int nrows) {
  __shared__ h16 As[128][K + 8];
  __shared__ h16 Ws[FOUT][K + 8];
  const int tid = threadIdx.x;
  const int wave = tid >> 6, lane = tid & 63;
  const int row0 = blockIdx.x * 128;
  const int fr = lane & 15;
  const int kb = (lane >> 4) * 8;
  constexpr int NF = FOUT / 16;
  const int rb = row0 + wave * 32 + (lane >> 4) * 4;

  float mean[2][NF][4] = {};

  for (int h = 0; h < 4; h++) {
    constexpr int AV = 128 * K / 8;
    for (int i = tid; i < AV; i += 256) {
      int r = i / (K / 8), kc = (i % (K / 8)) * 8;
      int row = row0 + r;
      h16x8 hv = {};
      if (row < nrows) hv = *(const h16x8*)&aggH[((size_t)row * 4 + h) * K + kc];
      *(h16x8*)&As[r][kc] = hv;
    }
    {
      int c = tid % FOUT;
      for (int k = tid / FOUT; k < K; k += 256 / FOUT)
        Ws[c][k] = Wa[(size_t)k * 4 * FOUT + h * FOUT + c];
    }
    __syncthreads();

    f32x4 acc[2][NF];
#pragma unroll
    for (int a = 0; a < 2; a++)
#pragma unroll
      for (int b = 0; b < NF; b++) acc[a][b] = (f32x4){0.f, 0.f, 0.f, 0.f};
#pragma unroll
    for (int k0 = 0; k0 < K; k0 += 32) {
      h16x8 af[2], bf[NF];
#pragma unroll
      for (int mf = 0; mf < 2; mf++)
        af[mf] = *(const h16x8*)&As[wave * 32 + mf * 16 + fr][k0 + kb];
#pragma unroll
      for (int nf = 0; nf < NF; nf++)
        bf[nf] = *(const h16x8*)&Ws[nf * 16 + fr][k0 + kb];
#pragma unroll
      for (int mf = 0; mf < 2; mf++)
#pragma unroll
        for (int nf = 0; nf < NF; nf++)
          acc[mf][nf] = __builtin_amdgcn_mfma_f32_16x16x32_f16(af[mf], bf[nf], acc[mf][nf], 0, 0, 0);
    }
#pragma unroll
    for (int nf = 0; nf < NF; nf++) {
      float bv = ba[h * FOUT + nf * 16 + fr];
#pragma unroll
      for (int mf = 0; mf < 2; mf++)
#pragma unroll
        for (int reg = 0; reg < 4; reg++)
          mean[mf][nf][reg] += 0.25f * fmaxf(acc[mf][nf][reg] + bv, 0.f);
    }
    __syncthreads();
  }

  if constexpr (FINAL) {
    float wp0 = Wp[fr], wp1 = Wp[16 + fr];
    float bp0 = bp[0];
#pragma unroll
    for (int mf = 0; mf < 2; mf++)
#pragma unroll
      for (int reg = 0; reg < 4; reg++) {
        float y0 = mean[mf][0][reg], y1 = mean[mf][1][reg];
        float p = y0 * wp0 + y1 * wp1;
#pragma unroll
        for (int m = 1; m < 16; m <<= 1) p += __shfl_xor(p, m);
        p += bp0;
        float s = __expf(p);
        float x0 = y0 * s, x1 = y1 * s;
        float q = x0 * x0 + x1 * x1;
#pragma unroll
        for (int m = 1; m < 16; m <<= 1) q += __shfl_xor(q, m);
        float nrm = fmaxf(sqrtf(q), 1e-12f);
        int row = rb + mf * 16 + reg;
        if (row < nrows) {
          outf[(size_t)row * 32 + fr] = x0 / nrm;
          outf[(size_t)row * 32 + 16 + fr] = x1 / nrm;
        }
      }
  } else {
#pragma unroll
    for (int mf = 0; mf < 2; mf++)
#pragma unroll
      for (int reg = 0; reg < 4; reg++) {
        int row = rb + mf * 16 + reg;
        if (row < nrows) {
#pragma unroll
          for (int nf = 0; nf < NF; nf++)
            out[(size_t)row * FOUT + nf * 16 + fr] = (h16)mean[mf][nf][reg];
        }
      }
  }
}

// ----------------------------- launch -----------------------------
extern "C" void kernel_launch(void* const* d_in, const int* in_sizes, int n_in,
                              void* d_out, int out_size, void* d_ws, size_t ws_size,
                              hipStream_t stream) {
  (void)in_sizes; (void)n_in; (void)out_size; (void)ws_size;
  const float* x   = (const float*)d_in[0];
  const int*   ei  = (const int*)d_in[1];
  const float* W1l = (const float*)d_in[2];
  const float* b1l = (const float*)d_in[3];
  const float* W1r = (const float*)d_in[4];
  const float* Wa1 = (const float*)d_in[5];
  const float* as1 = (const float*)d_in[6];
  const float* ad1 = (const float*)d_in[7];
  const float* ba1 = (const float*)d_in[8];
  const float* W2l = (const float*)d_in[9];
  const float* b2l = (const float*)d_in[10];
  const float* W2r = (const float*)d_in[11];
  const float* Wa2 = (const float*)d_in[12];
  const float* as2 = (const float*)d_in[13];
  const float* ad2 = (const float*)d_in[14];
  const float* ba2 = (const float*)d_in[15];
  const float* W3l = (const float*)d_in[16];
  const float* b3l = (const float*)d_in[17];
  const float* W3r = (const float*)d_in[18];
  const float* Wa3 = (const float*)d_in[19];
  const float* as3 = (const float*)d_in[20];
  const float* ad3 = (const float*)d_in[21];
  const float* ba3 = (const float*)d_in[22];
  const float* Wp  = (const float*)d_in[23];
  const float* bp  = (const float*)d_in[24];
  float* out = (float*)d_out;

  char* ws = (char*)d_ws;
  size_t off = 0;
  auto alloc = [&](size_t bytes) -> void* {
    void* p = ws + off;
    off += (bytes + 255) & ~(size_t)255;
    return p;
  };
  int* deg      = (int*)alloc((size_t)NNODES * 4);
  int* offs     = (int*)alloc((size_t)(NNODES + 1) * 4);
  int* cursor   = (int*)alloc((size_t)NNODES * 4);
  int* csr      = (int*)alloc((size_t)NEDGES * 4);
  int* bsums    = (int*)alloc((size_t)SCAN_BLOCKS * 4);
  int* perm     = (int*)alloc((size_t)NNODES * 4);
  h16* Wc1h     = (h16*)alloc((size_t)128 * 128 * 2);
  h16* Wc2h     = (h16*)alloc((size_t)64 * 128 * 2);
  h16* Wc3h     = (h16*)alloc((size_t)64 * 64 * 2);
  h16* Wa1h     = (h16*)alloc((size_t)64 * 256 * 2);
  h16* Wa2h     = (h16*)alloc((size_t)64 * 256 * 2);
  h16* Wa3h     = (h16*)alloc((size_t)32 * 128 * 2);
  h16* aggH     = (h16*)alloc((size_t)NNODES * 256 * 2);  // [N][4][K]; aliased as hist partials
  h16* bufCD    = (h16*)alloc((size_t)NNODES * 128 * 2);  // [hl|hr]
  h16* bufB     = (h16*)alloc((size_t)NNODES * 64 * 2);   // layer io
  float* als    = (float*)alloc((size_t)NNODES * 4 * 4);
  float* ald    = (float*)alloc((size_t)NNODES * 4 * 4);
  float* us1    = (float*)alloc(4 * 64 * 4);
  float* ud1    = (float*)alloc(4 * 64 * 4);
  float* us2    = (float*)alloc(4 * 64 * 4);
  float* ud2    = (float*)alloc(4 * 64 * 4);
  float* us3    = (float*)alloc(4 * 32 * 4);
  float* ud3    = (float*)alloc(4 * 32 * 4);
  unsigned* mx  = (unsigned*)alloc(24 * 4);  // [als 3x4 | ald 3x4]

  int* part = (int*)aggH;                      // HPART * NNODES ints = 25.6 MB
  int* sc   = part + (size_t)HPART * NNODES;   // degree-sort strip counts (64*64)

  int eb = (NEDGES + 255) / 256;
  k_hist<<<dim3(HPART, HRANGES), 256, 0, stream>>>(ei + NEDGES, part, NEDGES);
  k_prep<<<256, 256, 0, stream>>>(W1l, W1r, W2l, W2r, W3l, W3r, Wa1, Wa2, Wa3,
                                  Wc1h, Wc2h, Wc3h, Wa1h, Wa2h, Wa3h, mx);
  k_uprep_all<<<3, 256, 0, stream>>>(Wa1, as1, ad1, Wa2, as2, ad2, Wa3, as3, ad3,
                                     us1, ud1, us2, ud2, us3, ud3);
  k_scan1<<<SCAN_BLOCKS, 256, 0, stream>>>(part, deg, bsums, NNODES);
  k_dsA<<<DSB, 256, 0, stream>>>(deg, sc, NNODES);
  k_dsB<<<1, 64, 0, stream>>>(sc);
  k_dsC<<<DSB, 256, 0, stream>>>(deg, sc, perm, NNODES);
  k_scan2<<<1, 128, 0, stream>>>(bsums, offs, NNODES);
  k_scan3<<<SCAN_BLOCKS, 256, 0, stream>>>(deg, bsums, offs, cursor, NNODES);
  for (int p = 0; p < FILL_PASSES; p++)
    k_fill<<<eb, 256, 0, stream>>>(ei, cursor, csr, NEDGES,
                                   p * FILL_RANGE, min((p + 1) * FILL_RANGE, NNODES));

  const int gx = (NNODES + 127) / 128;
  const int nb_sage64 = (NNODES + 31) / 32;
  const int nb_sage32 = (NNODES + 63) / 64;
  const int nb_g64    = (NNODES + 31) / 32;
  const int nb_g32    = (NNODES + 63) / 64;

  // ---- block 1 ----
  k_gemm<128, true><<<dim3(gx, 2), 256, 0, stream>>>(x, Wc1h, bufCD, NNODES, 128);
  k_sage_agg<64><<<nb_sage64, 256, 0, stream>>>(bufCD, b1l, offs, csr, perm, us1, ud1, bufB, als, ald, NNODES);
  k_headmax<<<64, 256, 0, stream>>>(als, ald, mx + 0, mx + 12, NNODES);
  k_gat_gather<64><<<nb_g64, 256, 0, stream>>>(bufB, als, ald, mx + 0, mx + 12, offs, csr, perm, aggH, NNODES);
  k_headgemm<64, 64, false><<<gx, 256, 0, stream>>>(aggH, Wa1h, ba1, bufB, nullptr, nullptr, nullptr, NNODES);

  // ---- block 2 ----
  k_gemm<64, false><<<dim3(gx, 2), 256, 0, stream>>>(bufB, Wc2h, bufCD, NNODES, 128);
  k_sage_agg<64><<<nb_sage64, 256, 0, stream>>>(bufCD, b2l, offs, csr, perm, us2, ud2, bufB, als, ald, NNODES);
  k_headmax<<<64, 256, 0, stream>>>(als, ald, mx + 4, mx + 16, NNODES);
  k_gat_gather<64><<<nb_g64, 256, 0, stream>>>(bufB, als, ald, mx + 4, mx + 16, offs, csr, perm, aggH, NNODES);
  k_headgemm<64, 64, false><<<gx, 256, 0, stream>>>(aggH, Wa2h, ba2, bufB, nullptr, nullptr, nullptr, NNODES);

  // ---- block 3 ----
  k_gemm<64, false><<<dim3(gx, 1), 256, 0, stream>>>(bufB, Wc3h, bufCD, NNODES, 64);
  k_sage_agg<32><<<nb_sage32, 256, 0, stream>>>(bufCD, b3l, offs, csr, perm, us3, ud3, bufB, als, ald, NNODES);
  k_headmax<<<64, 256, 0, stream>>>(als, ald, mx + 8, mx + 20, NNODES);
  k_gat_gather<32><<<nb_g32, 256, 0, stream>>>(bufB, als, ald, mx + 8, mx + 20, offs, csr, perm, aggH, NNODES);
  k_headgemm<32, 32, true><<<gx, 256, 0, stream>>>(aggH, Wa3h, ba3, nullptr, Wp, bp, out, NNODES);
}